// Round 5
// baseline (539.014 us; speedup 1.0000x reference)
//
#include <hip/hip_runtime.h>

// ---------- helpers ----------
__device__ __forceinline__ unsigned short f2bf(float f) {
  unsigned u = __builtin_bit_cast(unsigned, f);
  u = u + 0x7fffu + ((u >> 16) & 1u);      // RNE
  return (unsigned short)(u >> 16);
}
__device__ __forceinline__ float bf2f(unsigned short u) {
  return __builtin_bit_cast(float, ((unsigned)u) << 16);
}

typedef __bf16 bf16x8 __attribute__((ext_vector_type(8)));
typedef float  f32x4  __attribute__((ext_vector_type(4)));

#define GLD16(gp, lp) __builtin_amdgcn_global_load_lds( \
    (const __attribute__((address_space(1))) unsigned int*)(gp), \
    (__attribute__((address_space(3))) unsigned int*)(lp), 16, 0, 0)

// ---------- rmsnorm (+ optional residual) ----------
template<int HAS_DELTA, int WRITE_SUM, int WRITE_N32>
__global__ __launch_bounds__(256) void resrms_k(const float* __restrict__ xin,
    const float* __restrict__ delta, float* __restrict__ xsum,
    unsigned short* __restrict__ nbf, float* __restrict__ nf32) {
  int row = blockIdx.x, tid = threadIdx.x;
  size_t base = ((size_t)row << 10) + ((size_t)tid << 2);
  float4 v = *(const float4*)(xin + base);
  if (HAS_DELTA) {
    float4 d = *(const float4*)(delta + base);
    v.x += d.x; v.y += d.y; v.z += d.z; v.w += d.w;
  }
  if (WRITE_SUM) *(float4*)(xsum + base) = v;
  float ss = v.x*v.x + v.y*v.y + v.z*v.z + v.w*v.w;
  #pragma unroll
  for (int off = 32; off; off >>= 1) ss += __shfl_xor(ss, off);
  __shared__ float ws4[4];
  if ((tid & 63) == 0) ws4[tid >> 6] = ss;
  __syncthreads();
  float tot = ws4[0] + ws4[1] + ws4[2] + ws4[3];
  float sc = rsqrtf(tot * (1.0f / 1024.0f) + 1e-5f);
  *(ushort4*)(nbf + base) = make_ushort4(f2bf(v.x*sc), f2bf(v.y*sc), f2bf(v.z*sc), f2bf(v.w*sc));
  if (WRITE_N32) {
    float4 n; n.x = v.x*sc; n.y = v.y*sc; n.z = v.z*sc; n.w = v.w*sc;
    *(float4*)(nf32 + base) = n;
  }
}

// ---------- transpose+convert: W[K][ldw] f32 -> Wt[Npad][K] bf16 ----------
__global__ void transp_k(const float* __restrict__ W, unsigned short* __restrict__ Wt,
                         int K, int Ncols, int Npad, int col_off, int ldw) {
  __shared__ float t[32][33];
  int n0 = blockIdx.x << 5, k0 = blockIdx.y << 5;
  int tx = threadIdx.x, ty = threadIdx.y;
  #pragma unroll
  for (int rr = 0; rr < 32; rr += 8) {
    int k = k0 + rr + ty, n = n0 + tx;
    t[rr + ty][tx] = (n < Ncols) ? W[(size_t)k * ldw + col_off + n] : 0.f;
  }
  __syncthreads();
  #pragma unroll
  for (int rr = 0; rr < 32; rr += 8) {
    int nrow = n0 + rr + ty;
    Wt[(size_t)nrow * K + k0 + tx] = f2bf(t[tx][rr + ty]);
  }
}

// ---------- bf16 MFMA GEMM, phase-pipelined: C[M][N] = A[M][K] * Bt[N][K]^T ----------
// BM=256, BN=128, BK=64. 512 threads = 8 waves (4M x 2N), wave tile 64x64, acc 4x4.
// 3 rotating LDS buffers (48KB each), prefetch distance 2 K-tiles, counted vmcnt(6).
// 2 phases per K-tile (kh = k-half), each: {8 ds_read_b128 || half stage -> barrier ->
// setprio 16 MFMA -> [vmcnt] barrier}. LDS XOR swizzle: phys_chunk = c ^ (row&7),
// applied both sides (inverse-permuted global source, linear DMA dest).
// EPI: 0 = f32 store, 1 = bf16 store, 2 = erf-activation -> bf16 store
template<int EPI>
__global__ __launch_bounds__(512) void gemm3_k(const unsigned short* __restrict__ A,
    const unsigned short* __restrict__ Bt, void* __restrict__ Cout,
    int M, int N, int K, int ntx) {
  __shared__ unsigned short lds3[3 * 24576];   // per buf: A 256x64 (32KB) + B 128x64 (16KB)
  const int tid = threadIdx.x;
  const int w = tid >> 6, lane = tid & 63;
  const int fr = lane & 15, g = lane >> 4;
  // XCD-aware bijective block swizzle (all grids here are %8==0)
  const int nwg = gridDim.x;
  const int sid = (blockIdx.x & 7) * (nwg >> 3) + (blockIdx.x >> 3);
  const int by = sid / ntx, bx = sid - by * ntx;
  const int m0 = by << 8, n0 = bx << 7;
  const int wm = (w >> 1) << 6;       // 0/64/128/192
  const int wn = (w & 1) << 6;        // 0/64

  f32x4 acc[4][4];
  #pragma unroll
  for (int i = 0; i < 4; ++i)
    #pragma unroll
    for (int j = 0; j < 4; ++j) acc[i][j] = (f32x4){0.f, 0.f, 0.f, 0.f};

  // staging source (inverse-swizzled per-lane addr; DMA dest is linear)
  const int lrow = tid >> 3;                    // 0..63
  const int lc   = (tid & 7) ^ (lrow & 7);      // logical chunk for this phys slot
  const unsigned short* a_src = A + (size_t)(m0 + lrow) * K + (lc << 3);
  const unsigned short* b_src = Bt + (size_t)(n0 + lrow) * K + (lc << 3);
  const size_t k64 = (size_t)64 * K, k128 = (size_t)128 * K, k192 = (size_t)192 * K;
  const int wofs = w << 9;

#define STAGE_A(kt_, bb_) { \
    const unsigned short* s_ = a_src + ((kt_) << 6); \
    unsigned short* d_ = lds3 + (bb_) * 24576 + wofs; \
    GLD16(s_, d_); GLD16(s_ + k64, d_ + 4096); \
    GLD16(s_ + k128, d_ + 8192); GLD16(s_ + k192, d_ + 12288); }
#define STAGE_B(kt_, bb_) { \
    const unsigned short* s_ = b_src + ((kt_) << 6); \
    unsigned short* d_ = lds3 + (bb_) * 24576 + 16384 + wofs; \
    GLD16(s_, d_); GLD16(s_ + k64, d_ + 4096); }

  // fragment read offsets (shorts), swizzled: chunk = (kh*4+g) ^ (fr&7)
  const int frq = fr & 7;
  const int c0 = (g ^ frq) << 3;
  const int c1 = ((4 + g) ^ frq) << 3;
  int aoff[4], boff[4];
  #pragma unroll
  for (int i = 0; i < 4; ++i) aoff[i] = (wm + (i << 4) + fr) << 6;
  #pragma unroll
  for (int j = 0; j < 4; ++j) boff[j] = 16384 + ((wn + (j << 4) + fr) << 6);

  const int NT = K >> 6;
  // prologue: stage tiles 0,1 -> bufs 0,1; wait tile 0 (6 newest = tile 1 outstanding)
  STAGE_A(0, 0) STAGE_B(0, 0)
  STAGE_A(1, 1) STAGE_B(1, 1)
  asm volatile("s_waitcnt vmcnt(6)" ::: "memory");
  __builtin_amdgcn_s_barrier();
  __builtin_amdgcn_sched_barrier(0);

  int cb = 0;
  for (int t = 0; t < NT; ++t) {
    const unsigned short* bufp = lds3 + cb * 24576;
    int sb = cb + 2; if (sb >= 3) sb -= 3;
    const int have2 = (t + 2 < NT);
    // ---- phase 0 (kh=0) ----
    bf16x8 af[4], bv[4];
    #pragma unroll
    for (int i = 0; i < 4; ++i) af[i] = *(const bf16x8*)&bufp[aoff[i] + c0];
    #pragma unroll
    for (int j = 0; j < 4; ++j) bv[j] = *(const bf16x8*)&bufp[boff[j] + c0];
    if (have2) STAGE_A(t + 2, sb)
    __builtin_amdgcn_s_barrier();
    __builtin_amdgcn_s_setprio(1);
    #pragma unroll
    for (int i = 0; i < 4; ++i)
      #pragma unroll
      for (int j = 0; j < 4; ++j)
        acc[i][j] = __builtin_amdgcn_mfma_f32_16x16x32_bf16(af[i], bv[j], acc[i][j], 0, 0, 0);
    __builtin_amdgcn_s_setprio(0);
    __builtin_amdgcn_s_barrier();
    __builtin_amdgcn_sched_barrier(0);
    // ---- phase 1 (kh=1) ----
    #pragma unroll
    for (int i = 0; i < 4; ++i) af[i] = *(const bf16x8*)&bufp[aoff[i] + c1];
    #pragma unroll
    for (int j = 0; j < 4; ++j) bv[j] = *(const bf16x8*)&bufp[boff[j] + c1];
    if (have2) STAGE_B(t + 2, sb)
    __builtin_amdgcn_s_barrier();
    __builtin_amdgcn_s_setprio(1);
    #pragma unroll
    for (int i = 0; i < 4; ++i)
      #pragma unroll
      for (int j = 0; j < 4; ++j)
        acc[i][j] = __builtin_amdgcn_mfma_f32_16x16x32_bf16(af[i], bv[j], acc[i][j], 0, 0, 0);
    __builtin_amdgcn_s_setprio(0);
    if (t + 1 < NT) {
      if (have2) { asm volatile("s_waitcnt vmcnt(6)" ::: "memory"); }
      else       { asm volatile("s_waitcnt vmcnt(0)" ::: "memory"); }
      __builtin_amdgcn_s_barrier();
      __builtin_amdgcn_sched_barrier(0);
    }
    cb = cb + 1; if (cb >= 3) cb -= 3;
  }
#undef STAGE_A
#undef STAGE_B

  const int rin = g << 2;
  #pragma unroll
  for (int i = 0; i < 4; ++i) {
    #pragma unroll
    for (int j = 0; j < 4; ++j) {
      int col = n0 + wn + (j << 4) + fr;
      if (col < N) {
        #pragma unroll
        for (int rr = 0; rr < 4; ++rr) {
          int row = m0 + wm + (i << 4) + rin + rr;
          float v = acc[i][j][rr];
          if (EPI == 0) {
            ((float*)Cout)[(size_t)row * N + col] = v;
          } else if (EPI == 1) {
            ((unsigned short*)Cout)[(size_t)row * N + col] = f2bf(v);
          } else {
            float kv = 0.5f * (1.0f + erff((v - 0.70710678f) * 2.5066283f));
            ((unsigned short*)Cout)[(size_t)row * N + col] = f2bf(kv);
          }
        }
      }
    }
  }
}

// ---------- dt ----------
__global__ __launch_bounds__(256) void dtk(const float* __restrict__ zxr,
    const float* __restrict__ dt_bias, float* __restrict__ dt) {
  int i = blockIdx.x * 256 + threadIdx.x;     // 4096*32
  int r = i >> 5, hh = i & 31;
  float v = zxr[(size_t)r * 2208 + 2176 + hh] + dt_bias[hh];
  float dtv = (v > 20.f) ? v : log1pf(__expf(v));
  dt[i] = dtv;
}

// ---------- causal depthwise conv(4) + silu ----------
__global__ __launch_bounds__(256) void convk(const float* __restrict__ zxr,
    const float* __restrict__ conv_w, const float* __restrict__ conv_b,
    float* __restrict__ xbc) {
  int i = blockIdx.x * 256 + threadIdx.x;     // 4*1024*2176
  if (i >= 4 * 1024 * 2176) return;
  int c = i % 2176; int bt = i / 2176; int t = bt & 1023;
  const float* col = zxr + (size_t)bt * 2208 + c;
  float acc = conv_b[c];
  float w0 = conv_w[c * 4 + 0], w1 = conv_w[c * 4 + 1], w2 = conv_w[c * 4 + 2], w3 = conv_w[c * 4 + 3];
  if (t >= 3) acc = fmaf(col[-3 * 2208], w0, acc);
  if (t >= 2) acc = fmaf(col[-2 * 2208], w1, acc);
  if (t >= 1) acc = fmaf(col[-1 * 2208], w2, acc);
  acc = fmaf(col[0], w3, acc);
  xbc[(size_t)bt * 2176 + c] = acc / (1.f + __expf(-acc));
}

// ---------- SSD chunked scan, stage 1 ----------
__global__ __launch_bounds__(256) void ssd1_k(const float* __restrict__ xbc,
    const float* __restrict__ dtb, const float* __restrict__ A_log,
    float* __restrict__ ydin, float* __restrict__ dhbuf, float* __restrict__ labuf) {
  __shared__ unsigned short Cs[64][68];   // [t][d]
  __shared__ unsigned short Bsm[64][68];  // [s][d]
  __shared__ unsigned short XT[64][68];   // [p][s]
  __shared__ unsigned short BT[64][68];   // [n][s] (scaled)
  __shared__ unsigned short Ms[64][68];   // [t][s]
  __shared__ float laS[64], dtS[64];
  const int id = blockIdx.x;
  const int h = id & 31, b = (id >> 5) & 3, c = id >> 7;
  const int tid = threadIdx.x, w = tid >> 6, lane = tid & 63;
  const int fr = lane & 15, g = lane >> 4;
  const size_t rowbase = (size_t)((b << 10) + (c << 6));

  {
    int r = tid >> 2, c0 = (tid & 3) << 4;
    const float* src = xbc + (rowbase + r) * 2176;
    #pragma unroll
    for (int i = 0; i < 4; ++i) {
      float4 v = *(const float4*)(src + 2112 + c0 + 4 * i);
      *(ushort4*)&Cs[r][c0 + 4 * i] = make_ushort4(f2bf(v.x), f2bf(v.y), f2bf(v.z), f2bf(v.w));
      float4 u = *(const float4*)(src + 2048 + c0 + 4 * i);
      *(ushort4*)&Bsm[r][c0 + 4 * i] = make_ushort4(f2bf(u.x), f2bf(u.y), f2bf(u.z), f2bf(u.w));
    }
  }
  {
    int r0 = (tid & 15) << 2, d0 = (tid >> 4) << 2;
    const float* src = xbc + (rowbase + r0) * 2176 + (h << 6) + d0;
    float4 v0 = *(const float4*)(src);
    float4 v1 = *(const float4*)(src + 2176);
    float4 v2 = *(const float4*)(src + 4352);
    float4 v3 = *(const float4*)(src + 6528);
    *(ushort4*)&XT[d0 + 0][r0] = make_ushort4(f2bf(v0.x), f2bf(v1.x), f2bf(v2.x), f2bf(v3.x));
    *(ushort4*)&XT[d0 + 1][r0] = make_ushort4(f2bf(v0.y), f2bf(v1.y), f2bf(v2.y), f2bf(v3.y));
    *(ushort4*)&XT[d0 + 2][r0] = make_ushort4(f2bf(v0.z), f2bf(v1.z), f2bf(v2.z), f2bf(v3.z));
    *(ushort4*)&XT[d0 + 3][r0] = make_ushort4(f2bf(v0.w), f2bf(v1.w), f2bf(v2.w), f2bf(v3.w));
  }
  if (w == 0) {
    float Ah = -__expf(A_log[h]);
    float dtv = dtb[(rowbase + lane) * 32 + h];
    float v = dtv * Ah;
    #pragma unroll
    for (int off = 1; off < 64; off <<= 1) {
      float u = __shfl_up(v, off);
      if (lane >= off) v += u;
    }
    laS[lane] = v; dtS[lane] = dtv;
    labuf[(size_t)((((b << 4) | c) << 5 | h) << 6) + lane] = v;
  }
  __syncthreads();

  const int wr = w >> 1, wc = w & 1;
  f32x4 gf[2][2];
  #pragma unroll
  for (int i = 0; i < 2; ++i)
    #pragma unroll
    for (int j = 0; j < 2; ++j) gf[i][j] = (f32x4){0.f, 0.f, 0.f, 0.f};
  {
    int r0 = (tid & 15) << 2, d0 = (tid >> 4) << 2;
    const float* src = xbc + (rowbase + r0) * 2176 + 2048 + d0;
    float la63 = laS[63];
    float4 v0 = *(const float4*)(src);
    float4 v1 = *(const float4*)(src + 2176);
    float4 v2 = *(const float4*)(src + 4352);
    float4 v3 = *(const float4*)(src + 6528);
    float w0 = __expf(la63 - laS[r0 + 0]) * dtS[r0 + 0];
    float w1 = __expf(la63 - laS[r0 + 1]) * dtS[r0 + 1];
    float w2 = __expf(la63 - laS[r0 + 2]) * dtS[r0 + 2];
    float w3 = __expf(la63 - laS[r0 + 3]) * dtS[r0 + 3];
    *(ushort4*)&BT[d0 + 0][r0] = make_ushort4(f2bf(v0.x*w0), f2bf(v1.x*w1), f2bf(v2.x*w2), f2bf(v3.x*w3));
    *(ushort4*)&BT[d0 + 1][r0] = make_ushort4(f2bf(v0.y*w0), f2bf(v1.y*w1), f2bf(v2.y*w2), f2bf(v3.y*w3));
    *(ushort4*)&BT[d0 + 2][r0] = make_ushort4(f2bf(v0.z*w0), f2bf(v1.z*w1), f2bf(v2.z*w2), f2bf(v3.z*w3));
    *(ushort4*)&BT[d0 + 3][r0] = make_ushort4(f2bf(v0.w*w0), f2bf(v1.w*w1), f2bf(v2.w*w2), f2bf(v3.w*w3));
  }
  #pragma unroll
  for (int ks = 0; ks < 2; ++ks) {
    bf16x8 ca[2], bb[2];
    #pragma unroll
    for (int i = 0; i < 2; ++i) ca[i] = *(const bf16x8*)&Cs[(wr << 5) + (i << 4) + fr][(ks << 5) + (g << 3)];
    #pragma unroll
    for (int j = 0; j < 2; ++j) bb[j] = *(const bf16x8*)&Bsm[(wc << 5) + (j << 4) + fr][(ks << 5) + (g << 3)];
    #pragma unroll
    for (int i = 0; i < 2; ++i)
      #pragma unroll
      for (int j = 0; j < 2; ++j)
        gf[i][j] = __builtin_amdgcn_mfma_f32_16x16x32_bf16(ca[i], bb[j], gf[i][j], 0, 0, 0);
  }
  #pragma unroll
  for (int i = 0; i < 2; ++i) {
    #pragma unroll
    for (int j = 0; j < 2; ++j) {
      int s = (wc << 5) + (j << 4) + fr;
      float la_s = laS[s], dt_s = dtS[s];
      #pragma unroll
      for (int rr = 0; rr < 4; ++rr) {
        int t = (wr << 5) + (i << 4) + (g << 2) + rr;
        float e = __expf(fminf(laS[t] - la_s, 0.f));
        float val = (s <= t) ? gf[i][j][rr] * e * dt_s : 0.f;
        Ms[t][s] = f2bf(val);
      }
    }
  }
  __syncthreads();

  f32x4 yf[2][2], hf[2][2];
  #pragma unroll
  for (int i = 0; i < 2; ++i)
    #pragma unroll
    for (int j = 0; j < 2; ++j) { yf[i][j] = (f32x4){0.f,0.f,0.f,0.f}; hf[i][j] = (f32x4){0.f,0.f,0.f,0.f}; }
  #pragma unroll
  for (int ks = 0; ks < 2; ++ks) {
    bf16x8 ma[2], ba[2], xb[2];
    #pragma unroll
    for (int i = 0; i < 2; ++i) {
      ma[i] = *(const bf16x8*)&Ms[(wr << 5) + (i << 4) + fr][(ks << 5) + (g << 3)];
      ba[i] = *(const bf16x8*)&BT[(wr << 5) + (i << 4) + fr][(ks << 5) + (g << 3)];
    }
    #pragma unroll
    for (int j = 0; j < 2; ++j) xb[j] = *(const bf16x8*)&XT[(wc << 5) + (j << 4) + fr][(ks << 5) + (g << 3)];
    #pragma unroll
    for (int i = 0; i < 2; ++i)
      #pragma unroll
      for (int j = 0; j < 2; ++j) {
        yf[i][j] = __builtin_amdgcn_mfma_f32_16x16x32_bf16(ma[i], xb[j], yf[i][j], 0, 0, 0);
        hf[i][j] = __builtin_amdgcn_mfma_f32_16x16x32_bf16(ba[i], xb[j], hf[i][j], 0, 0, 0);
      }
  }
  float* dhb = dhbuf + ((size_t)(((c << 2) + b) * 32 + h) << 12);
  #pragma unroll
  for (int i = 0; i < 2; ++i) {
    #pragma unroll
    for (int j = 0; j < 2; ++j) {
      int p = (wc << 5) + (j << 4) + fr;
      #pragma unroll
      for (int rr = 0; rr < 4; ++rr) {
        int t = (wr << 5) + (i << 4) + (g << 2) + rr;
        ydin[((rowbase + t) << 11) + (h << 6) + p] = yf[i][j][rr];
        dhb[(t << 6) + p] = hf[i][j][rr];
      }
    }
  }
}

// ---------- SSD stage 2 ----------
__global__ __launch_bounds__(256) void ssd2_k(const float* __restrict__ dhbuf,
    const float* __restrict__ labuf, float* __restrict__ hseq) {
  int idx = blockIdx.x * 256 + threadIdx.x;   // 524288 = b*h*n*p
  int np = idx & 4095;
  int h = (idx >> 12) & 31, b = idx >> 17;
  float carry = 0.f;
  #pragma unroll
  for (int c = 0; c < 16; ++c) {
    size_t o = ((size_t)(((c << 2) + b) * 32 + h) << 12) + np;
    hseq[o] = carry;
    float ec = __expf(labuf[(size_t)((((b << 4) | c) << 5 | h) << 6) + 63]);
    carry = fmaf(ec, carry, dhbuf[o]);
  }
}

// ---------- SSD stage 3 ----------
__global__ __launch_bounds__(256) void ssd3_k(const float* __restrict__ xbc,
    const float* __restrict__ hseq, const float* __restrict__ labuf,
    const float* __restrict__ Dv, float* __restrict__ ydin) {
  __shared__ unsigned short Cs[64][68];
  __shared__ unsigned short HT[64][68];
  __shared__ float laS[64];
  const int id = blockIdx.x;
  const int h = id & 31, b = (id >> 5) & 3, c = id >> 7;
  const int tid = threadIdx.x, w = tid >> 6, lane = tid & 63;
  const int fr = lane & 15, g = lane >> 4;
  const size_t rowbase = (size_t)((b << 10) + (c << 6));
  {
    int r = tid >> 2, c0 = (tid & 3) << 4;
    const float* src = xbc + (rowbase + r) * 2176 + 2112 + c0;
    #pragma unroll
    for (int i = 0; i < 4; ++i) {
      float4 v = *(const float4*)(src + 4 * i);
      *(ushort4*)&Cs[r][c0 + 4 * i] = make_ushort4(f2bf(v.x), f2bf(v.y), f2bf(v.z), f2bf(v.w));
    }
  }
  {
    const float* hb = hseq + ((size_t)(((c << 2) + b) * 32 + h) << 12);
    int n0 = (tid & 15) << 2, p0 = (tid >> 4) << 2;
    float4 v0 = *(const float4*)(hb + ((n0 + 0) << 6) + p0);
    float4 v1 = *(const float4*)(hb + ((n0 + 1) << 6) + p0);
    float4 v2 = *(const float4*)(hb + ((n0 + 2) << 6) + p0);
    float4 v3 = *(const float4*)(hb + ((n0 + 3) << 6) + p0);
    *(ushort4*)&HT[p0 + 0][n0] = make_ushort4(f2bf(v0.x), f2bf(v1.x), f2bf(v2.x), f2bf(v3.x));
    *(ushort4*)&HT[p0 + 1][n0] = make_ushort4(f2bf(v0.y), f2bf(v1.y), f2bf(v2.y), f2bf(v3.y));
    *(ushort4*)&HT[p0 + 2][n0] = make_ushort4(f2bf(v0.z), f2bf(v1.z), f2bf(v2.z), f2bf(v3.z));
    *(ushort4*)&HT[p0 + 3][n0] = make_ushort4(f2bf(v0.w), f2bf(v1.w), f2bf(v2.w), f2bf(v3.w));
  }
  if (tid < 64) laS[tid] = labuf[(size_t)((((b << 4) | c) << 5 | h) << 6) + tid];
  __syncthreads();
  const int wr = w >> 1, wc = w & 1;
  f32x4 yf[2][2];
  #pragma unroll
  for (int i = 0; i < 2; ++i)
    #pragma unroll
    for (int j = 0; j < 2; ++j) yf[i][j] = (f32x4){0.f, 0.f, 0.f, 0.f};
  #pragma unroll
  for (int ks = 0; ks < 2; ++ks) {
    bf16x8 ca[2], hv[2];
    #pragma unroll
    for (int i = 0; i < 2; ++i) ca[i] = *(const bf16x8*)&Cs[(wr << 5) + (i << 4) + fr][(ks << 5) + (g << 3)];
    #pragma unroll
    for (int j = 0; j < 2; ++j) hv[j] = *(const bf16x8*)&HT[(wc << 5) + (j << 4) + fr][(ks << 5) + (g << 3)];
    #pragma unroll
    for (int i = 0; i < 2; ++i)
      #pragma unroll
      for (int j = 0; j < 2; ++j)
        yf[i][j] = __builtin_amdgcn_mfma_f32_16x16x32_bf16(ca[i], hv[j], yf[i][j], 0, 0, 0);
  }
  float Dh = Dv[h];
  #pragma unroll
  for (int i = 0; i < 2; ++i) {
    #pragma unroll
    for (int j = 0; j < 2; ++j) {
      int p = (wc << 5) + (j << 4) + fr;
      #pragma unroll
      for (int rr = 0; rr < 4; ++rr) {
        int t = (wr << 5) + (i << 4) + (g << 2) + rr;
        size_t yo = ((rowbase + t) << 11) + (h << 6) + p;
        float xv = xbc[(rowbase + t) * 2176 + (h << 6) + p];
        ydin[yo] = ydin[yo] + __expf(laS[t]) * yf[i][j][rr] + Dh * xv;
      }
    }
  }
}

// ---------- g = ydin * silu(z); rmsnorm(2048) * mnorm_w -> bf16 ----------
__global__ __launch_bounds__(256) void gnormk(const float* __restrict__ ydin,
    const unsigned short* __restrict__ zbf, const float* __restrict__ mw,
    unsigned short* __restrict__ gbf) {
  int row = blockIdx.x, tid = threadIdx.x;
  size_t base = ((size_t)row << 11) + ((size_t)tid << 3);
  float4 y0 = *(const float4*)(ydin + base);
  float4 y1 = *(const float4*)(ydin + base + 4);
  ushort4 z0 = *(const ushort4*)(zbf + base);
  ushort4 z1 = *(const ushort4*)(zbf + base + 4);
  float g[8];
  {
    float z;
    z = bf2f(z0.x); g[0] = y0.x * (z / (1.f + __expf(-z)));
    z = bf2f(z0.y); g[1] = y0.y * (z / (1.f + __expf(-z)));
    z = bf2f(z0.z); g[2] = y0.z * (z / (1.f + __expf(-z)));
    z = bf2f(z0.w); g[3] = y0.w * (z / (1.f + __expf(-z)));
    z = bf2f(z1.x); g[4] = y1.x * (z / (1.f + __expf(-z)));
    z = bf2f(z1.y); g[5] = y1.y * (z / (1.f + __expf(-z)));
    z = bf2f(z1.z); g[6] = y1.z * (z / (1.f + __expf(-z)));
    z = bf2f(z1.w); g[7] = y1.w * (z / (1.f + __expf(-z)));
  }
  float ss = 0.f;
  #pragma unroll
  for (int k = 0; k < 8; ++k) ss += g[k] * g[k];
  #pragma unroll
  for (int off = 32; off; off >>= 1) ss += __shfl_xor(ss, off);
  __shared__ float ws4[4];
  if ((tid & 63) == 0) ws4[tid >> 6] = ss;
  __syncthreads();
  float tot = ws4[0] + ws4[1] + ws4[2] + ws4[3];
  float sc = rsqrtf(tot * (1.f / 2048.f) + 1e-5f);
  int c0 = tid << 3;
  float4 m0 = *(const float4*)(mw + c0);
  float4 m1 = *(const float4*)(mw + c0 + 4);
  *(ushort4*)(gbf + base)     = make_ushort4(f2bf(g[0]*sc*m0.x), f2bf(g[1]*sc*m0.y), f2bf(g[2]*sc*m0.z), f2bf(g[3]*sc*m0.w));
  *(ushort4*)(gbf + base + 4) = make_ushort4(f2bf(g[4]*sc*m1.x), f2bf(g[5]*sc*m1.y), f2bf(g[6]*sc*m1.z), f2bf(g[7]*sc*m1.w));
}

// ---------- MQA causal attention (MFMA flash), out bf16 ----------
__global__ __launch_bounds__(256) void attnk(const float* __restrict__ qkv,
                                             unsigned short* __restrict__ ybf) {
  __shared__ unsigned short Qs[64][72];
  __shared__ unsigned short Ks[64][72];
  __shared__ unsigned short VT[64][72];
  __shared__ unsigned short Ps[4][16][72];
  const int id = blockIdx.x;
  const int b = id & 3, h = (id >> 2) & 15, qt = id >> 6;
  const int t0 = qt << 6;
  const int tid = threadIdx.x, w = tid >> 6, lane = tid & 63;
  const int fr = lane & 15, g = lane >> 4;
  {
    int r = tid >> 2, d0 = (tid & 3) << 4;
    const float* src = qkv + ((size_t)((b << 10) | (t0 + r))) * 1152 + (h << 6) + d0;
    #pragma unroll
    for (int i = 0; i < 4; ++i) {
      float4 v = *(const float4*)(src + 4 * i);
      *(ushort4*)&Qs[r][d0 + 4 * i] =
          make_ushort4(f2bf(v.x * 0.125f), f2bf(v.y * 0.125f), f2bf(v.z * 0.125f), f2bf(v.w * 0.125f));
    }
  }
  __syncthreads();
  bf16x8 afQ0 = *(const bf16x8*)&Qs[(w << 4) + fr][g << 3];
  bf16x8 afQ1 = *(const bf16x8*)&Qs[(w << 4) + fr][32 + (g << 3)];
  f32x4 acc_o[4];
  #pragma unroll
  for (int i = 0; i < 4; ++i) acc_o[i] = (f32x4){0.f, 0.f, 0.f, 0.f};
  float m[4] = {-1e30f, -1e30f, -1e30f, -1e30f};
  float l[4] = {0.f, 0.f, 0.f, 0.f};
  const int qrow = t0 + (w << 4) + (g << 2);
  for (int kt = 0; kt <= qt; ++kt) {
    const int s0 = kt << 6;
    __syncthreads();
    {
      int r = tid >> 2, d0 = (tid & 3) << 4;
      const float* src = qkv + ((size_t)((b << 10) | (s0 + r))) * 1152 + 1024 + d0;
      #pragma unroll
      for (int i = 0; i < 4; ++i) {
        float4 v = *(const float4*)(src + 4 * i);
        *(ushort4*)&Ks[r][d0 + 4 * i] = make_ushort4(f2bf(v.x), f2bf(v.y), f2bf(v.z), f2bf(v.w));
      }
    }
    {
      int r0 = (tid & 15) << 2, d0 = (tid >> 4) << 2;
      const float* src = qkv + ((size_t)((b << 10) | (s0 + r0))) * 1152 + 1088 + d0;
      float4 v0 = *(const float4*)(src);
      float4 v1 = *(const float4*)(src + 1152);
      float4 v2 = *(const float4*)(src + 2304);
      float4 v3 = *(const float4*)(src + 3456);
      *(ushort4*)&VT[d0 + 0][r0] = make_ushort4(f2bf(v0.x), f2bf(v1.x), f2bf(v2.x), f2bf(v3.x));
      *(ushort4*)&VT[d0 + 1][r0] = make_ushort4(f2bf(v0.y), f2bf(v1.y), f2bf(v2.y), f2bf(v3.y));
      *(ushort4*)&VT[d0 + 2][r0] = make_ushort4(f2bf(v0.z), f2bf(v1.z), f2bf(v2.z), f2bf(v3.z));
      *(ushort4*)&VT[d0 + 3][r0] = make_ushort4(f2bf(v0.w), f2bf(v1.w), f2bf(v2.w), f2bf(v3.w));
    }
    __syncthreads();
    f32x4 s4[4];
    #pragma unroll
    for (int jt = 0; jt < 4; ++jt) {
      bf16x8 b0 = *(const bf16x8*)&Ks[(jt << 4) + fr][g << 3];
      bf16x8 b1 = *(const bf16x8*)&Ks[(jt << 4) + fr][32 + (g << 3)];
      f32x4 z4 = (f32x4){0.f, 0.f, 0.f, 0.f};
      z4 = __builtin_amdgcn_mfma_f32_16x16x32_bf16(afQ0, b0, z4, 0, 0, 0);
      z4 = __builtin_amdgcn_mfma_f32_16x16x32_bf16(afQ1, b1, z4, 0, 0, 0);
      s4[jt] = z4;
    }
    if (kt == qt) {
      #pragma unroll
      for (int jt = 0; jt < 4; ++jt) {
        int key = s0 + (jt << 4) + fr;
        #pragma unroll
        for (int r = 0; r < 4; ++r)
          if (key > qrow + r) s4[jt][r] = -1e30f;
      }
    }
    #pragma unroll
    for (int r = 0; r < 4; ++r) {
      float mt = fmaxf(fmaxf(s4[0][r], s4[1][r]), fmaxf(s4[2][r], s4[3][r]));
      #pragma unroll
      for (int off = 8; off; off >>= 1) mt = fmaxf(mt, __shfl_xor(mt, off));
      float mn = fmaxf(m[r], mt);
      float scl = __expf(m[r] - mn);
      m[r] = mn;
      float ps = 0.f;
      #pragma unroll
      for (int jt = 0; jt < 4; ++jt) {
        float p = __expf(s4[jt][r] - mn);
        ps += p;
        Ps[w][(g << 2) + r][(jt << 4) + fr] = f2bf(p);
      }
      #pragma unroll
      for (int off = 8; off; off >>= 1) ps += __shfl_xor(ps, off);
      l[r] = l[r] * scl + ps;
      acc_o[0][r] *= scl; acc_o[1][r] *= scl; acc_o[2][r] *= scl; acc_o[3][r] *= scl;
    }
    #pragma unroll
    for (int ks = 0; ks < 2; ++ks) {
      bf16x8 ap = *(const bf16x8*)&Ps[w][fr][(ks << 5) + (g << 3)];
      #pragma unroll
      for (int dt = 0; dt < 4; ++dt) {
        bf16x8 bv = *(const bf16x8*)&VT[(dt << 4) + fr][(ks << 5) + (g << 3)];
        acc_o[dt] = __builtin_amdgcn_mfma_f32_16x16x32_bf16(ap, bv, acc_o[dt], 0, 0, 0);
      }
    }
  }
  #pragma unroll
  for (int dt = 0; dt < 4; ++dt) {
    #pragma unroll
    for (int r = 0; r < 4; ++r) {
      float o = acc_o[dt][r] / l[r];
      int t = t0 + (w << 4) + (g << 2) + r;
      ybf[(((size_t)((b << 10) | t)) << 10) + (h << 6) + (dt << 4) + fr] = f2bf(o);
    }
  }
}

// ---------- cmix token-shift mix -> xk, xr (bf16) ----------
__global__ __launch_bounds__(256) void mixk(const float* __restrict__ xn3,
    const float* __restrict__ tmk, const float* __restrict__ tmr,
    unsigned short* __restrict__ xkbf, unsigned short* __restrict__ xrbf) {
  int idx4 = blockIdx.x * 256 + threadIdx.x;
  int col = (idx4 & 255) << 2;
  int row = idx4 >> 8;
  int t = row & 1023;
  size_t off = ((size_t)idx4) << 2;
  float4 cur = *(const float4*)(xn3 + off);
  float4 prev = make_float4(0.f, 0.f, 0.f, 0.f);
  if (t > 0) prev = *(const float4*)(xn3 + off - 1024);
  float4 tk = *(const float4*)(tmk + col);
  float4 tr = *(const float4*)(tmr + col);
  float dx = prev.x - cur.x, dy = prev.y - cur.y, dz = prev.z - cur.z, dw = prev.w - cur.w;
  *(ushort4*)(xkbf + off) = make_ushort4(
      f2bf(cur.x + dx * tk.x), f2bf(cur.y + dy * tk.y), f2bf(cur.z + dz * tk.z), f2bf(cur.w + dw * tk.w));
  *(ushort4*)(xrbf + off) = make_ushort4(
      f2bf(cur.x + dx * tr.x), f2bf(cur.y + dy * tr.y), f2bf(cur.z + dz * tr.z), f2bf(cur.w + dw * tr.w));
}

// ---------- final: out = x2 + sigmoid(rraw) * vout ----------
__global__ __launch_bounds__(256) void finalk(const float* __restrict__ x2,
    const float* __restrict__ rraw, const float* __restrict__ vout,
    float* __restrict__ out) {
  int idx4 = blockIdx.x * 256 + threadIdx.x;
  size_t off = ((size_t)idx4) << 2;
  float4 xv = *(const float4*)(x2 + off);
  float4 rv = *(const float4*)(rraw + off);
  float4 vv = *(const float4*)(vout + off);
  float4 o;
  o.x = xv.x + vv.x / (1.f + __expf(-rv.x));
  o.y = xv.y + vv.y / (1.f + __expf(-rv.y));
  o.z = xv.z + vv.z / (1.f + __expf(-rv.z));
  o.w = xv.w + vv.w / (1.f + __expf(-rv.w));
  *(float4*)(out + off) = o;
}

// ---------- host launcher ----------
extern "C" void kernel_launch(void* const* d_in, const int* in_sizes, int n_in,
                              void* d_out, int out_size, void* d_ws, size_t ws_size,
                              hipStream_t stream) {
  (void)in_sizes; (void)n_in; (void)out_size;
  const float* x        = (const float*)d_in[0];
  const float* in_proj  = (const float*)d_in[1];
  const float* conv_w   = (const float*)d_in[2];
  const float* conv_b   = (const float*)d_in[3];
  const float* dt_bias  = (const float*)d_in[4];
  const float* A_log    = (const float*)d_in[5];
  const float* Dvec     = (const float*)d_in[6];
  const float* mnorm_w  = (const float*)d_in[7];
  const float* out_proj = (const float*)d_in[8];
  const float* attn_w   = (const float*)d_in[9];
  const float* proj_w   = (const float*)d_in[10];
  const float* tmk      = (const float*)d_in[11];
  const float* tmr      = (const float*)d_in[12];
  const float* key_w    = (const float*)d_in[13];
  const float* recept_w = (const float*)d_in[14];
  const float* value_w  = (const float*)d_in[15];
  float* out = (float*)d_out;

  if (ws_size < 199229440ull) return;

  char* ws = (char*)d_ws;
  unsigned short* Wt   = (unsigned short*)(ws + 0);
  unsigned short* Abf  = (unsigned short*)(ws + 8912896ull);
  unsigned short* Abf2 = (unsigned short*)(ws + 42467328ull);
  float* bigF = (float*)(ws + 59244544ull);
  float* big1 = (float*)(ws + 95420416ull);
  float* big2 = (float*)(ws + 131072000ull);
  float* x1   = (float*)(ws + 164626432ull);
  float* xn3  = (float*)(ws + 181403648ull);
  float* dtb  = (float*)(ws + 198180864ull);
  float* labuf= (float*)(ws + 198705152ull);
  unsigned short* zbf  = Abf2;
  unsigned short* xkbf = Abf2;
  unsigned short* xrbf = Abf2 + 4194304;
  float* dhbuf = bigF;
  float* hseq  = (float*)Abf;

  dim3 b256(256);
  dim3 b512(512);
  dim3 tb(32, 8);

  // ===== Phase A: mamba2 =====
  resrms_k<0, 0, 0><<<4096, b256, 0, stream>>>(x, nullptr, nullptr, Abf, nullptr);
  transp_k<<<dim3(64, 32), tb, 0, stream>>>(in_proj, Wt, 1024, 2048, 2048, 0, 4256);
  gemm3_k<1><<<256, b512, 0, stream>>>(Abf, Wt, zbf, 4096, 2048, 1024, 16);              // z (bf16)
  transp_k<<<dim3(72, 32), tb, 0, stream>>>(in_proj, Wt, 1024, 2208, 2304, 2048, 4256);
  gemm3_k<0><<<288, b512, 0, stream>>>(Abf, Wt, bigF, 4096, 2208, 1024, 18);             // xBC+dt (f32)
  dtk<<<512, b256, 0, stream>>>(bigF, dt_bias, dtb);
  convk<<<34816, b256, 0, stream>>>(bigF, conv_w, conv_b, big1);                         // xbc_act
  ssd1_k<<<2048, b256, 0, stream>>>(big1, dtb, A_log, big2, dhbuf, labuf);               // Y_intra, dh, la
  ssd2_k<<<2048, b256, 0, stream>>>(dhbuf, labuf, hseq);                                 // chunk states
  ssd3_k<<<2048, b256, 0, stream>>>(big1, hseq, labuf, Dvec, big2);                      // ydin final
  gnormk<<<4096, b256, 0, stream>>>(big2, zbf, mnorm_w, Abf);                            // g (bf16)
  transp_k<<<dim3(32, 64), tb, 0, stream>>>(out_proj, Wt, 2048, 1024, 1024, 0, 1024);
  gemm3_k<0><<<128, b512, 0, stream>>>(Abf, Wt, big1, 4096, 1024, 2048, 8);              // mo
  resrms_k<1, 1, 0><<<4096, b256, 0, stream>>>(x, big1, x1, Abf, nullptr);               // x1, xn2

  // ===== Phase B: mqa =====
  transp_k<<<dim3(36, 32), tb, 0, stream>>>(attn_w, Wt, 1024, 1152, 1152, 0, 1152);
  gemm3_k<0><<<144, b512, 0, stream>>>(Abf, Wt, big1, 4096, 1152, 1024, 9);              // qkv
  attnk<<<1024, b256, 0, stream>>>(big1, Abf);                                           // atty (bf16)
  transp_k<<<dim3(32, 32), tb, 0, stream>>>(proj_w, Wt, 1024, 1024, 1024, 0, 1024);
  gemm3_k<0><<<128, b512, 0, stream>>>(Abf, Wt, big2, 4096, 1024, 1024, 8);              // po
  resrms_k<1, 1, 1><<<4096, b256, 0, stream>>>(x1, big2, x1, Abf, xn3);                  // x2 (in x1), xn3

  // ===== Phase C: cmix =====
  mixk<<<4096, b256, 0, stream>>>(xn3, tmk, tmr, xkbf, xrbf);
  transp_k<<<dim3(128, 32), tb, 0, stream>>>(key_w, Wt, 1024, 4096, 4096, 0, 4096);
  gemm3_k<2><<<512, b512, 0, stream>>>(xkbf, Wt, Abf, 4096, 4096, 1024, 32);             // kact (bf16)
  transp_k<<<dim3(32, 128), tb, 0, stream>>>(value_w, Wt, 4096, 1024, 1024, 0, 1024);
  gemm3_k<0><<<128, b512, 0, stream>>>(Abf, Wt, big2, 4096, 1024, 4096, 8);              // vout
  transp_k<<<dim3(32, 32), tb, 0, stream>>>(recept_w, Wt, 1024, 1024, 1024, 0, 1024);
  gemm3_k<0><<<128, b512, 0, stream>>>(xrbf, Wt, big1, 4096, 1024, 1024, 8);             // rraw
  finalk<<<4096, b256, 0, stream>>>(x1, big1, big2, out);
}

// Round 7
// 536.748 us; speedup vs baseline: 1.0042x; 1.0042x over previous
//
#include <hip/hip_runtime.h>

// ---------- helpers ----------
__device__ __forceinline__ unsigned short f2bf(float f) {
  unsigned u = __builtin_bit_cast(unsigned, f);
  u = u + 0x7fffu + ((u >> 16) & 1u);      // RNE
  return (unsigned short)(u >> 16);
}
__device__ __forceinline__ float bf2f(unsigned short u) {
  return __builtin_bit_cast(float, ((unsigned)u) << 16);
}

typedef __bf16 bf16x8 __attribute__((ext_vector_type(8)));
typedef float  f32x4  __attribute__((ext_vector_type(4)));
typedef unsigned short u16x8 __attribute__((ext_vector_type(8)));

#define GLD16(gp, lp) __builtin_amdgcn_global_load_lds( \
    (const __attribute__((address_space(1))) unsigned int*)(gp), \
    (__attribute__((address_space(3))) unsigned int*)(lp), 16, 0, 0)

// ---------- rmsnorm (+ optional residual) ----------
template<int HAS_DELTA, int WRITE_SUM, int WRITE_N32>
__global__ __launch_bounds__(256) void resrms_k(const float* __restrict__ xin,
    const float* __restrict__ delta, float* __restrict__ xsum,
    unsigned short* __restrict__ nbf, float* __restrict__ nf32) {
  int row = blockIdx.x, tid = threadIdx.x;
  size_t base = ((size_t)row << 10) + ((size_t)tid << 2);
  float4 v = *(const float4*)(xin + base);
  if (HAS_DELTA) {
    float4 d = *(const float4*)(delta + base);
    v.x += d.x; v.y += d.y; v.z += d.z; v.w += d.w;
  }
  if (WRITE_SUM) *(float4*)(xsum + base) = v;
  float ss = v.x*v.x + v.y*v.y + v.z*v.z + v.w*v.w;
  #pragma unroll
  for (int off = 32; off; off >>= 1) ss += __shfl_xor(ss, off);
  __shared__ float ws4[4];
  if ((tid & 63) == 0) ws4[tid >> 6] = ss;
  __syncthreads();
  float tot = ws4[0] + ws4[1] + ws4[2] + ws4[3];
  float sc = rsqrtf(tot * (1.0f / 1024.0f) + 1e-5f);
  *(ushort4*)(nbf + base) = make_ushort4(f2bf(v.x*sc), f2bf(v.y*sc), f2bf(v.z*sc), f2bf(v.w*sc));
  if (WRITE_N32) {
    float4 n; n.x = v.x*sc; n.y = v.y*sc; n.z = v.z*sc; n.w = v.w*sc;
    *(float4*)(nf32 + base) = n;
  }
}

// ---------- transpose+convert: W[K][ldw] f32 -> Wt[Npad][K] bf16 ----------
__global__ void transp_k(const float* __restrict__ W, unsigned short* __restrict__ Wt,
                         int K, int Ncols, int Npad, int col_off, int ldw) {
  __shared__ float t[32][33];
  int n0 = blockIdx.x << 5, k0 = blockIdx.y << 5;
  int tx = threadIdx.x, ty = threadIdx.y;
  #pragma unroll
  for (int rr = 0; rr < 32; rr += 8) {
    int k = k0 + rr + ty, n = n0 + tx;
    t[rr + ty][tx] = (n < Ncols) ? W[(size_t)k * ldw + col_off + n] : 0.f;
  }
  __syncthreads();
  #pragma unroll
  for (int rr = 0; rr < 32; rr += 8) {
    int nrow = n0 + rr + ty;
    Wt[(size_t)nrow * K + k0 + tx] = f2bf(t[tx][rr + ty]);
  }
}

// ---------- bf16 MFMA GEMM (m97-class, 3 blk/CU): C[M][N] = A[M][K] * Bt[N][K]^T ----------
// BM=BN=128, BK=32, 256 threads = 4 waves (2Mx2N), wave tile 64x64, acc 4x4.
// 3 rotating LDS buffers (16KB each), prefetch distance 2, counted vmcnt(4), raw barriers.
// Chunk-XOR swizzle: phys = c ^ ((row>>1)&3), applied both sides (2-way = free).
// Epilogue through LDS (reuses staging mem): contiguous 16B per-lane stores, no C-line RMW.
// EPI: 0 = f32 store, 1 = bf16 store, 2 = erf-activation -> bf16 store
template<int EPI>
__global__ __launch_bounds__(256, 3) void gemm4_k(const unsigned short* __restrict__ A,
    const unsigned short* __restrict__ Bt, void* __restrict__ Cout,
    int M, int N, int K, int ntx) {
  __shared__ char smem[49152];            // 3 x (A 8KB + B 8KB); epilogue reuses 33.8KB
  unsigned short* lds = (unsigned short*)smem;
  const int tid = threadIdx.x;
  const int w = tid >> 6, lane = tid & 63;
  const int fr = lane & 15, g = lane >> 4;
  // XCD-aware bijective block swizzle (all grids %8==0)
  const int nwg = gridDim.x;
  const int sid = (blockIdx.x & 7) * (nwg >> 3) + (blockIdx.x >> 3);
  const int by = sid / ntx, bx = sid - by * ntx;
  const int m0 = by << 7, n0 = bx << 7;
  const int wm = (w >> 1) << 6, wn = (w & 1) << 6;

  f32x4 acc[4][4];
  #pragma unroll
  for (int i = 0; i < 4; ++i)
    #pragma unroll
    for (int j = 0; j < 4; ++j) acc[i][j] = (f32x4){0.f, 0.f, 0.f, 0.f};

  // staging: slot s in {tid, tid+256}; row=s>>2, phys chunk=s&3, logical=phys^((row>>1)&3)
  const int r0s = tid >> 2, pc0 = tid & 3;
  const int lc0 = pc0 ^ ((r0s >> 1) & 3);
  const int r1s = r0s + 64;
  const int lc1 = pc0 ^ ((r1s >> 1) & 3);
  const unsigned short* a0 = A + (size_t)(m0 + r0s) * K + (lc0 << 3);
  const unsigned short* a1 = A + (size_t)(m0 + r1s) * K + (lc1 << 3);
  const unsigned short* b0 = Bt + (size_t)(n0 + r0s) * K + (lc0 << 3);
  const unsigned short* b1 = Bt + (size_t)(n0 + r1s) * K + (lc1 << 3);
  const int wofs = w << 9;   // wave slot: 64 lanes x 8 shorts = 512 shorts per wave per instr

#define STAGE4(kt_, bb_) { \
    unsigned short* d_ = lds + (bb_) * 8192 + wofs; \
    GLD16(a0 + ((kt_) << 5), d_); \
    GLD16(a1 + ((kt_) << 5), d_ + 2048); \
    GLD16(b0 + ((kt_) << 5), d_ + 4096); \
    GLD16(b1 + ((kt_) << 5), d_ + 6144); }

  const int NT = K >> 5;
  STAGE4(0, 0)
  STAGE4(1, 1)
  asm volatile("s_waitcnt vmcnt(4)" ::: "memory");
  __builtin_amdgcn_s_barrier();
  __builtin_amdgcn_sched_barrier(0);

  int cb = 0;
  for (int t = 0; t < NT; ++t) {
    const unsigned short* bufp = lds + cb * 8192;
    int sb = cb + 2; if (sb >= 3) sb -= 3;
    const int have2 = (t + 2 < NT);
    if (have2) STAGE4(t + 2, sb)
    bf16x8 af[4], bv[4];
    #pragma unroll
    for (int i = 0; i < 4; ++i) {
      int r = wm + (i << 4) + fr;
      af[i] = *(const bf16x8*)&bufp[(r << 5) + (((g ^ (r >> 1)) & 3) << 3)];
    }
    #pragma unroll
    for (int j = 0; j < 4; ++j) {
      int r = wn + (j << 4) + fr;
      bv[j] = *(const bf16x8*)&bufp[4096 + (r << 5) + (((g ^ (r >> 1)) & 3) << 3)];
    }
    __builtin_amdgcn_s_setprio(1);
    #pragma unroll
    for (int i = 0; i < 4; ++i)
      #pragma unroll
      for (int j = 0; j < 4; ++j)
        acc[i][j] = __builtin_amdgcn_mfma_f32_16x16x32_bf16(af[i], bv[j], acc[i][j], 0, 0, 0);
    __builtin_amdgcn_s_setprio(0);
    if (t + 1 < NT) {
      if (have2) { asm volatile("s_waitcnt vmcnt(4)" ::: "memory"); }
      else       { asm volatile("s_waitcnt vmcnt(0)" ::: "memory"); }
      __builtin_amdgcn_s_barrier();
      __builtin_amdgcn_sched_barrier(0);
    }
    cb = cb + 1; if (cb >= 3) cb -= 3;
  }
#undef STAGE4

  // ---- epilogue via LDS: contiguous 16B stores (full __syncthreads: cross-wave ds_write->ds_read) ----
  float (*eps)[132] = (float(*)[132])smem;   // 64 x 132 f32 = 33792B
  const int rin = g << 2;
  const int er = tid >> 2, ec0 = (tid & 3) << 5;
  #pragma unroll
  for (int rh = 0; rh < 2; ++rh) {
    __syncthreads();
    if ((wm >> 6) == rh) {
      #pragma unroll
      for (int i = 0; i < 4; ++i)
        #pragma unroll
        for (int j = 0; j < 4; ++j)
          #pragma unroll
          for (int rr = 0; rr < 4; ++rr)
            eps[(i << 4) + rin + rr][wn + (j << 4) + fr] = acc[i][j][rr];
    }
    __syncthreads();
    int grow = m0 + (rh << 6) + er;
    if (EPI == 0) {
      float* orow = (float*)Cout + (size_t)grow * N + n0 + ec0;
      #pragma unroll
      for (int u = 0; u < 8; ++u) {
        int col = n0 + ec0 + (u << 2);
        if (col < N) {
          float4 v; v.x = eps[er][ec0 + (u<<2)]; v.y = eps[er][ec0 + (u<<2) + 1];
          v.z = eps[er][ec0 + (u<<2) + 2]; v.w = eps[er][ec0 + (u<<2) + 3];
          *(float4*)(orow + (u << 2)) = v;
        }
      }
    } else {
      unsigned short* orow = (unsigned short*)Cout + (size_t)grow * N + n0 + ec0;
      #pragma unroll
      for (int u = 0; u < 4; ++u) {
        int col = n0 + ec0 + (u << 3);
        if (col < N) {
          u16x8 pk;
          #pragma unroll
          for (int e = 0; e < 8; ++e) {
            float v = eps[er][ec0 + (u << 3) + e];
            if (EPI == 2) v = 0.5f * (1.0f + erff((v - 0.70710678f) * 2.5066283f));
            pk[e] = f2bf(v);
          }
          *(u16x8*)(orow + (u << 3)) = pk;
        }
      }
    }
  }
}

// ---------- dt ----------
__global__ __launch_bounds__(256) void dtk(const float* __restrict__ zxr,
    const float* __restrict__ dt_bias, float* __restrict__ dt) {
  int i = blockIdx.x * 256 + threadIdx.x;     // 4096*32
  int r = i >> 5, hh = i & 31;
  float v = zxr[(size_t)r * 2208 + 2176 + hh] + dt_bias[hh];
  float dtv = (v > 20.f) ? v : log1pf(__expf(v));
  dt[i] = dtv;
}

// ---------- causal depthwise conv(4) + silu ----------
__global__ __launch_bounds__(256) void convk(const float* __restrict__ zxr,
    const float* __restrict__ conv_w, const float* __restrict__ conv_b,
    float* __restrict__ xbc) {
  int i = blockIdx.x * 256 + threadIdx.x;     // 4*1024*2176
  if (i >= 4 * 1024 * 2176) return;
  int c = i % 2176; int bt = i / 2176; int t = bt & 1023;
  const float* col = zxr + (size_t)bt * 2208 + c;
  float acc = conv_b[c];
  float w0 = conv_w[c * 4 + 0], w1 = conv_w[c * 4 + 1], w2 = conv_w[c * 4 + 2], w3 = conv_w[c * 4 + 3];
  if (t >= 3) acc = fmaf(col[-3 * 2208], w0, acc);
  if (t >= 2) acc = fmaf(col[-2 * 2208], w1, acc);
  if (t >= 1) acc = fmaf(col[-1 * 2208], w2, acc);
  acc = fmaf(col[0], w3, acc);
  xbc[(size_t)bt * 2176 + c] = acc / (1.f + __expf(-acc));
}

// ---------- SSD chunked scan, stage 1 ----------
__global__ __launch_bounds__(256) void ssd1_k(const float* __restrict__ xbc,
    const float* __restrict__ dtb, const float* __restrict__ A_log,
    float* __restrict__ ydin, float* __restrict__ dhbuf, float* __restrict__ labuf) {
  __shared__ unsigned short Cs[64][68];   // [t][d]
  __shared__ unsigned short Bsm[64][68];  // [s][d]
  __shared__ unsigned short XT[64][68];   // [p][s]
  __shared__ unsigned short BT[64][68];   // [n][s] (scaled)
  __shared__ unsigned short Ms[64][68];   // [t][s]
  __shared__ float laS[64], dtS[64];
  const int id = blockIdx.x;
  const int h = id & 31, b = (id >> 5) & 3, c = id >> 7;
  const int tid = threadIdx.x, w = tid >> 6, lane = tid & 63;
  const int fr = lane & 15, g = lane >> 4;
  const size_t rowbase = (size_t)((b << 10) + (c << 6));

  {
    int r = tid >> 2, c0 = (tid & 3) << 4;
    const float* src = xbc + (rowbase + r) * 2176;
    #pragma unroll
    for (int i = 0; i < 4; ++i) {
      float4 v = *(const float4*)(src + 2112 + c0 + 4 * i);
      *(ushort4*)&Cs[r][c0 + 4 * i] = make_ushort4(f2bf(v.x), f2bf(v.y), f2bf(v.z), f2bf(v.w));
      float4 u = *(const float4*)(src + 2048 + c0 + 4 * i);
      *(ushort4*)&Bsm[r][c0 + 4 * i] = make_ushort4(f2bf(u.x), f2bf(u.y), f2bf(u.z), f2bf(u.w));
    }
  }
  {
    int r0 = (tid & 15) << 2, d0 = (tid >> 4) << 2;
    const float* src = xbc + (rowbase + r0) * 2176 + (h << 6) + d0;
    float4 v0 = *(const float4*)(src);
    float4 v1 = *(const float4*)(src + 2176);
    float4 v2 = *(const float4*)(src + 4352);
    float4 v3 = *(const float4*)(src + 6528);
    *(ushort4*)&XT[d0 + 0][r0] = make_ushort4(f2bf(v0.x), f2bf(v1.x), f2bf(v2.x), f2bf(v3.x));
    *(ushort4*)&XT[d0 + 1][r0] = make_ushort4(f2bf(v0.y), f2bf(v1.y), f2bf(v2.y), f2bf(v3.y));
    *(ushort4*)&XT[d0 + 2][r0] = make_ushort4(f2bf(v0.z), f2bf(v1.z), f2bf(v2.z), f2bf(v3.z));
    *(ushort4*)&XT[d0 + 3][r0] = make_ushort4(f2bf(v0.w), f2bf(v1.w), f2bf(v2.w), f2bf(v3.w));
  }
  if (w == 0) {
    float Ah = -__expf(A_log[h]);
    float dtv = dtb[(rowbase + lane) * 32 + h];
    float v = dtv * Ah;
    #pragma unroll
    for (int off = 1; off < 64; off <<= 1) {
      float u = __shfl_up(v, off);
      if (lane >= off) v += u;
    }
    laS[lane] = v; dtS[lane] = dtv;
    labuf[(size_t)((((b << 4) | c) << 5 | h) << 6) + lane] = v;
  }
  __syncthreads();

  const int wr = w >> 1, wc = w & 1;
  f32x4 gf[2][2];
  #pragma unroll
  for (int i = 0; i < 2; ++i)
    #pragma unroll
    for (int j = 0; j < 2; ++j) gf[i][j] = (f32x4){0.f, 0.f, 0.f, 0.f};
  {
    int r0 = (tid & 15) << 2, d0 = (tid >> 4) << 2;
    const float* src = xbc + (rowbase + r0) * 2176 + 2048 + d0;
    float la63 = laS[63];
    float4 v0 = *(const float4*)(src);
    float4 v1 = *(const float4*)(src + 2176);
    float4 v2 = *(const float4*)(src + 4352);
    float4 v3 = *(const float4*)(src + 6528);
    float w0 = __expf(la63 - laS[r0 + 0]) * dtS[r0 + 0];
    float w1 = __expf(la63 - laS[r0 + 1]) * dtS[r0 + 1];
    float w2 = __expf(la63 - laS[r0 + 2]) * dtS[r0 + 2];
    float w3 = __expf(la63 - laS[r0 + 3]) * dtS[r0 + 3];
    *(ushort4*)&BT[d0 + 0][r0] = make_ushort4(f2bf(v0.x*w0), f2bf(v1.x*w1), f2bf(v2.x*w2), f2bf(v3.x*w3));
    *(ushort4*)&BT[d0 + 1][r0] = make_ushort4(f2bf(v0.y*w0), f2bf(v1.y*w1), f2bf(v2.y*w2), f2bf(v3.y*w3));
    *(ushort4*)&BT[d0 + 2][r0] = make_ushort4(f2bf(v0.z*w0), f2bf(v1.z*w1), f2bf(v2.z*w2), f2bf(v3.z*w3));
    *(ushort4*)&BT[d0 + 3][r0] = make_ushort4(f2bf(v0.w*w0), f2bf(v1.w*w1), f2bf(v2.w*w2), f2bf(v3.w*w3));
  }
  #pragma unroll
  for (int ks = 0; ks < 2; ++ks) {
    bf16x8 ca[2], bb[2];
    #pragma unroll
    for (int i = 0; i < 2; ++i) ca[i] = *(const bf16x8*)&Cs[(wr << 5) + (i << 4) + fr][(ks << 5) + (g << 3)];
    #pragma unroll
    for (int j = 0; j < 2; ++j) bb[j] = *(const bf16x8*)&Bsm[(wc << 5) + (j << 4) + fr][(ks << 5) + (g << 3)];
    #pragma unroll
    for (int i = 0; i < 2; ++i)
      #pragma unroll
      for (int j = 0; j < 2; ++j)
        gf[i][j] = __builtin_amdgcn_mfma_f32_16x16x32_bf16(ca[i], bb[j], gf[i][j], 0, 0, 0);
  }
  #pragma unroll
  for (int i = 0; i < 2; ++i) {
    #pragma unroll
    for (int j = 0; j < 2; ++j) {
      int s = (wc << 5) + (j << 4) + fr;
      float la_s = laS[s], dt_s = dtS[s];
      #pragma unroll
      for (int rr = 0; rr < 4; ++rr) {
        int t = (wr << 5) + (i << 4) + (g << 2) + rr;
        float e = __expf(fminf(laS[t] - la_s, 0.f));
        float val = (s <= t) ? gf[i][j][rr] * e * dt_s : 0.f;
        Ms[t][s] = f2bf(val);
      }
    }
  }
  __syncthreads();

  f32x4 yf[2][2], hf[2][2];
  #pragma unroll
  for (int i = 0; i < 2; ++i)
    #pragma unroll
    for (int j = 0; j < 2; ++j) { yf[i][j] = (f32x4){0.f,0.f,0.f,0.f}; hf[i][j] = (f32x4){0.f,0.f,0.f,0.f}; }
  #pragma unroll
  for (int ks = 0; ks < 2; ++ks) {
    bf16x8 ma[2], ba[2], xb[2];
    #pragma unroll
    for (int i = 0; i < 2; ++i) {
      ma[i] = *(const bf16x8*)&Ms[(wr << 5) + (i << 4) + fr][(ks << 5) + (g << 3)];
      ba[i] = *(const bf16x8*)&BT[(wr << 5) + (i << 4) + fr][(ks << 5) + (g << 3)];
    }
    #pragma unroll
    for (int j = 0; j < 2; ++j) xb[j] = *(const bf16x8*)&XT[(wc << 5) + (j << 4) + fr][(ks << 5) + (g << 3)];
    #pragma unroll
    for (int i = 0; i < 2; ++i)
      #pragma unroll
      for (int j = 0; j < 2; ++j) {
        yf[i][j] = __builtin_amdgcn_mfma_f32_16x16x32_bf16(ma[i], xb[j], yf[i][j], 0, 0, 0);
        hf[i][j] = __builtin_amdgcn_mfma_f32_16x16x32_bf16(ba[i], xb[j], hf[i][j], 0, 0, 0);
      }
  }
  float* dhb = dhbuf + ((size_t)(((c << 2) + b) * 32 + h) << 12);
  #pragma unroll
  for (int i = 0; i < 2; ++i) {
    #pragma unroll
    for (int j = 0; j < 2; ++j) {
      int p = (wc << 5) + (j << 4) + fr;
      #pragma unroll
      for (int rr = 0; rr < 4; ++rr) {
        int t = (wr << 5) + (i << 4) + (g << 2) + rr;
        ydin[((rowbase + t) << 11) + (h << 6) + p] = yf[i][j][rr];
        dhb[(t << 6) + p] = hf[i][j][rr];
      }
    }
  }
}

// ---------- SSD stage 2 ----------
__global__ __launch_bounds__(256) void ssd2_k(const float* __restrict__ dhbuf,
    const float* __restrict__ labuf, float* __restrict__ hseq) {
  int idx = blockIdx.x * 256 + threadIdx.x;   // 524288 = b*h*n*p
  int np = idx & 4095;
  int h = (idx >> 12) & 31, b = idx >> 17;
  float carry = 0.f;
  #pragma unroll
  for (int c = 0; c < 16; ++c) {
    size_t o = ((size_t)(((c << 2) + b) * 32 + h) << 12) + np;
    hseq[o] = carry;
    float ec = __expf(labuf[(size_t)((((b << 4) | c) << 5 | h) << 6) + 63]);
    carry = fmaf(ec, carry, dhbuf[o]);
  }
}

// ---------- SSD stage 3 ----------
__global__ __launch_bounds__(256) void ssd3_k(const float* __restrict__ xbc,
    const float* __restrict__ hseq, const float* __restrict__ labuf,
    const float* __restrict__ Dv, float* __restrict__ ydin) {
  __shared__ unsigned short Cs[64][68];
  __shared__ unsigned short HT[64][68];
  __shared__ float laS[64];
  const int id = blockIdx.x;
  const int h = id & 31, b = (id >> 5) & 3, c = id >> 7;
  const int tid = threadIdx.x, w = tid >> 6, lane = tid & 63;
  const int fr = lane & 15, g = lane >> 4;
  const size_t rowbase = (size_t)((b << 10) + (c << 6));
  {
    int r = tid >> 2, c0 = (tid & 3) << 4;
    const float* src = xbc + (rowbase + r) * 2176 + 2112 + c0;
    #pragma unroll
    for (int i = 0; i < 4; ++i) {
      float4 v = *(const float4*)(src + 4 * i);
      *(ushort4*)&Cs[r][c0 + 4 * i] = make_ushort4(f2bf(v.x), f2bf(v.y), f2bf(v.z), f2bf(v.w));
    }
  }
  {
    const float* hb = hseq + ((size_t)(((c << 2) + b) * 32 + h) << 12);
    int n0 = (tid & 15) << 2, p0 = (tid >> 4) << 2;
    float4 v0 = *(const float4*)(hb + ((n0 + 0) << 6) + p0);
    float4 v1 = *(const float4*)(hb + ((n0 + 1) << 6) + p0);
    float4 v2 = *(const float4*)(hb + ((n0 + 2) << 6) + p0);
    float4 v3 = *(const float4*)(hb + ((n0 + 3) << 6) + p0);
    *(ushort4*)&HT[p0 + 0][n0] = make_ushort4(f2bf(v0.x), f2bf(v1.x), f2bf(v2.x), f2bf(v3.x));
    *(ushort4*)&HT[p0 + 1][n0] = make_ushort4(f2bf(v0.y), f2bf(v1.y), f2bf(v2.y), f2bf(v3.y));
    *(ushort4*)&HT[p0 + 2][n0] = make_ushort4(f2bf(v0.z), f2bf(v1.z), f2bf(v2.z), f2bf(v3.z));
    *(ushort4*)&HT[p0 + 3][n0] = make_ushort4(f2bf(v0.w), f2bf(v1.w), f2bf(v2.w), f2bf(v3.w));
  }
  if (tid < 64) laS[tid] = labuf[(size_t)((((b << 4) | c) << 5 | h) << 6) + tid];
  __syncthreads();
  const int wr = w >> 1, wc = w & 1;
  f32x4 yf[2][2];
  #pragma unroll
  for (int i = 0; i < 2; ++i)
    #pragma unroll
    for (int j = 0; j < 2; ++j) yf[i][j] = (f32x4){0.f, 0.f, 0.f, 0.f};
  #pragma unroll
  for (int ks = 0; ks < 2; ++ks) {
    bf16x8 ca[2], hv[2];
    #pragma unroll
    for (int i = 0; i < 2; ++i) ca[i] = *(const bf16x8*)&Cs[(wr << 5) + (i << 4) + fr][(ks << 5) + (g << 3)];
    #pragma unroll
    for (int j = 0; j < 2; ++j) hv[j] = *(const bf16x8*)&HT[(wc << 5) + (j << 4) + fr][(ks << 5) + (g << 3)];
    #pragma unroll
    for (int i = 0; i < 2; ++i)
      #pragma unroll
      for (int j = 0; j < 2; ++j)
        yf[i][j] = __builtin_amdgcn_mfma_f32_16x16x32_bf16(ca[i], hv[j], yf[i][j], 0, 0, 0);
  }
  float Dh = Dv[h];
  #pragma unroll
  for (int i = 0; i < 2; ++i) {
    #pragma unroll
    for (int j = 0; j < 2; ++j) {
      int p = (wc << 5) + (j << 4) + fr;
      #pragma unroll
      for (int rr = 0; rr < 4; ++rr) {
        int t = (wr << 5) + (i << 4) + (g << 2) + rr;
        size_t yo = ((rowbase + t) << 11) + (h << 6) + p;
        float xv = xbc[(rowbase + t) * 2176 + (h << 6) + p];
        ydin[yo] = ydin[yo] + __expf(laS[t]) * yf[i][j][rr] + Dh * xv;
      }
    }
  }
}

// ---------- g = ydin * silu(z); rmsnorm(2048) * mnorm_w -> bf16 ----------
__global__ __launch_bounds__(256) void gnormk(const float* __restrict__ ydin,
    const unsigned short* __restrict__ zbf, const float* __restrict__ mw,
    unsigned short* __restrict__ gbf) {
  int row = blockIdx.x, tid = threadIdx.x;
  size_t base = ((size_t)row << 11) + ((size_t)tid << 3);
  float4 y0 = *(const float4*)(ydin + base);
  float4 y1 = *(const float4*)(ydin + base + 4);
  ushort4 z0 = *(const ushort4*)(zbf + base);
  ushort4 z1 = *(const ushort4*)(zbf + base + 4);
  float g[8];
  {
    float z;
    z = bf2f(z0.x); g[0] = y0.x * (z / (1.f + __expf(-z)));
    z = bf2f(z0.y); g[1] = y0.y * (z / (1.f + __expf(-z)));
    z = bf2f(z0.z); g[2] = y0.z * (z / (1.f + __expf(-z)));
    z = bf2f(z0.w); g[3] = y0.w * (z / (1.f + __expf(-z)));
    z = bf2f(z1.x); g[4] = y1.x * (z / (1.f + __expf(-z)));
    z = bf2f(z1.y); g[5] = y1.y * (z / (1.f + __expf(-z)));
    z = bf2f(z1.z); g[6] = y1.z * (z / (1.f + __expf(-z)));
    z = bf2f(z1.w); g[7] = y1.w * (z / (1.f + __expf(-z)));
  }
  float ss = 0.f;
  #pragma unroll
  for (int k = 0; k < 8; ++k) ss += g[k] * g[k];
  #pragma unroll
  for (int off = 32; off; off >>= 1) ss += __shfl_xor(ss, off);
  __shared__ float ws4[4];
  if ((tid & 63) == 0) ws4[tid >> 6] = ss;
  __syncthreads();
  float tot = ws4[0] + ws4[1] + ws4[2] + ws4[3];
  float sc = rsqrtf(tot * (1.f / 2048.f) + 1e-5f);
  int c0 = tid << 3;
  float4 m0 = *(const float4*)(mw + c0);
  float4 m1 = *(const float4*)(mw + c0 + 4);
  *(ushort4*)(gbf + base)     = make_ushort4(f2bf(g[0]*sc*m0.x), f2bf(g[1]*sc*m0.y), f2bf(g[2]*sc*m0.z), f2bf(g[3]*sc*m0.w));
  *(ushort4*)(gbf + base + 4) = make_ushort4(f2bf(g[4]*sc*m1.x), f2bf(g[5]*sc*m1.y), f2bf(g[6]*sc*m1.z), f2bf(g[7]*sc*m1.w));
}

// ---------- MQA causal attention (MFMA flash), out bf16 ----------
__global__ __launch_bounds__(256) void attnk(const float* __restrict__ qkv,
                                             unsigned short* __restrict__ ybf) {
  __shared__ unsigned short Qs[64][72];
  __shared__ unsigned short Ks[64][72];
  __shared__ unsigned short VT[64][72];
  __shared__ unsigned short Ps[4][16][72];
  const int id = blockIdx.x;
  const int b = id & 3, h = (id >> 2) & 15, qt = id >> 6;
  const int t0 = qt << 6;
  const int tid = threadIdx.x, w = tid >> 6, lane = tid & 63;
  const int fr = lane & 15, g = lane >> 4;
  {
    int r = tid >> 2, d0 = (tid & 3) << 4;
    const float* src = qkv + ((size_t)((b << 10) | (t0 + r))) * 1152 + (h << 6) + d0;
    #pragma unroll
    for (int i = 0; i < 4; ++i) {
      float4 v = *(const float4*)(src + 4 * i);
      *(ushort4*)&Qs[r][d0 + 4 * i] =
          make_ushort4(f2bf(v.x * 0.125f), f2bf(v.y * 0.125f), f2bf(v.z * 0.125f), f2bf(v.w * 0.125f));
    }
  }
  __syncthreads();
  bf16x8 afQ0 = *(const bf16x8*)&Qs[(w << 4) + fr][g << 3];
  bf16x8 afQ1 = *(const bf16x8*)&Qs[(w << 4) + fr][32 + (g << 3)];
  f32x4 acc_o[4];
  #pragma unroll
  for (int i = 0; i < 4; ++i) acc_o[i] = (f32x4){0.f, 0.f, 0.f, 0.f};
  float m[4] = {-1e30f, -1e30f, -1e30f, -1e30f};
  float l[4] = {0.f, 0.f, 0.f, 0.f};
  const int qrow = t0 + (w << 4) + (g << 2);
  for (int kt = 0; kt <= qt; ++kt) {
    const int s0 = kt << 6;
    __syncthreads();
    {
      int r = tid >> 2, d0 = (tid & 3) << 4;
      const float* src = qkv + ((size_t)((b << 10) | (s0 + r))) * 1152 + 1024 + d0;
      #pragma unroll
      for (int i = 0; i < 4; ++i) {
        float4 v = *(const float4*)(src + 4 * i);
        *(ushort4*)&Ks[r][d0 + 4 * i] = make_ushort4(f2bf(v.x), f2bf(v.y), f2bf(v.z), f2bf(v.w));
      }
    }
    {
      int r0 = (tid & 15) << 2, d0 = (tid >> 4) << 2;
      const float* src = qkv + ((size_t)((b << 10) | (s0 + r0))) * 1152 + 1088 + d0;
      float4 v0 = *(const float4*)(src);
      float4 v1 = *(const float4*)(src + 1152);
      float4 v2 = *(const float4*)(src + 2304);
      float4 v3 = *(const float4*)(src + 3456);
      *(ushort4*)&VT[d0 + 0][r0] = make_ushort4(f2bf(v0.x), f2bf(v1.x), f2bf(v2.x), f2bf(v3.x));
      *(ushort4*)&VT[d0 + 1][r0] = make_ushort4(f2bf(v0.y), f2bf(v1.y), f2bf(v2.y), f2bf(v3.y));
      *(ushort4*)&VT[d0 + 2][r0] = make_ushort4(f2bf(v0.z), f2bf(v1.z), f2bf(v2.z), f2bf(v3.z));
      *(ushort4*)&VT[d0 + 3][r0] = make_ushort4(f2bf(v0.w), f2bf(v1.w), f2bf(v2.w), f2bf(v3.w));
    }
    __syncthreads();
    f32x4 s4[4];
    #pragma unroll
    for (int jt = 0; jt < 4; ++jt) {
      bf16x8 b0 = *(const bf16x8*)&Ks[(jt << 4) + fr][g << 3];
      bf16x8 b1 = *(const bf16x8*)&Ks[(jt << 4) + fr][32 + (g << 3)];
      f32x4 z4 = (f32x4){0.f, 0.f, 0.f, 0.f};
      z4 = __builtin_amdgcn_mfma_f32_16x16x32_bf16(afQ0, b0, z4, 0, 0, 0);
      z4 = __builtin_amdgcn_mfma_f32_16x16x32_bf16(afQ1, b1, z4, 0, 0, 0);
      s4[jt] = z4;
    }
    if (kt == qt) {
      #pragma unroll
      for (int jt = 0; jt < 4; ++jt) {
        int key = s0 + (jt << 4) + fr;
        #pragma unroll
        for (int r = 0; r < 4; ++r)
          if (key > qrow + r) s4[jt][r] = -1e30f;
      }
    }
    #pragma unroll
    for (int r = 0; r < 4; ++r) {
      float mt = fmaxf(fmaxf(s4[0][r], s4[1][r]), fmaxf(s4[2][r], s4[3][r]));
      #pragma unroll
      for (int off = 8; off; off >>= 1) mt = fmaxf(mt, __shfl_xor(mt, off));
      float mn = fmaxf(m[r], mt);
      float scl = __expf(m[r] - mn);
      m[r] = mn;
      float ps = 0.f;
      #pragma unroll
      for (int jt = 0; jt < 4; ++jt) {
        float p = __expf(s4[jt][r] - mn);
        ps += p;
        Ps[w][(g << 2) + r][(jt << 4) + fr] = f2bf(p);
      }
      #pragma unroll
      for (int off = 8; off; off >>= 1) ps += __shfl_xor(ps, off);
      l[r] = l[r] * scl + ps;
      acc_o[0][r] *= scl; acc_o[1][r] *= scl; acc_o[2][r] *= scl; acc_o[3][r] *= scl;
    }
    #pragma unroll
    for (int ks = 0; ks < 2; ++ks) {
      bf16x8 ap = *(const bf16x8*)&Ps[w][fr][(ks << 5) + (g << 3)];
      #pragma unroll
      for (int dt = 0; dt < 4; ++dt) {
        bf16x8 bv = *(const bf16x8*)&VT[(dt << 4) + fr][(ks << 5) + (g << 3)];
        acc_o[dt] = __builtin_amdgcn_mfma_f32_16x16x32_bf16(ap, bv, acc_o[dt], 0, 0, 0);
      }
    }
  }
  #pragma unroll
  for (int dt = 0; dt < 4; ++dt) {
    #pragma unroll
    for (int r = 0; r < 4; ++r) {
      float o = acc_o[dt][r] / l[r];
      int t = t0 + (w << 4) + (g << 2) + r;
      ybf[(((size_t)((b << 10) | t)) << 10) + (h << 6) + (dt << 4) + fr] = f2bf(o);
    }
  }
}

// ---------- cmix token-shift mix -> xk, xr (bf16) ----------
__global__ __launch_bounds__(256) void mixk(const float* __restrict__ xn3,
    const float* __restrict__ tmk, const float* __restrict__ tmr,
    unsigned short* __restrict__ xkbf, unsigned short* __restrict__ xrbf) {
  int idx4 = blockIdx.x * 256 + threadIdx.x;
  int col = (idx4 & 255) << 2;
  int row = idx4 >> 8;
  int t = row & 1023;
  size_t off = ((size_t)idx4) << 2;
  float4 cur = *(const float4*)(xn3 + off);
  float4 prev = make_float4(0.f, 0.f, 0.f, 0.f);
  if (t > 0) prev = *(const float4*)(xn3 + off - 1024);
  float4 tk = *(const float4*)(tmk + col);
  float4 tr = *(const float4*)(tmr + col);
  float dx = prev.x - cur.x, dy = prev.y - cur.y, dz = prev.z - cur.z, dw = prev.w - cur.w;
  *(ushort4*)(xkbf + off) = make_ushort4(
      f2bf(cur.x + dx * tk.x), f2bf(cur.y + dy * tk.y), f2bf(cur.z + dz * tk.z), f2bf(cur.w + dw * tk.w));
  *(ushort4*)(xrbf + off) = make_ushort4(
      f2bf(cur.x + dx * tr.x), f2bf(cur.y + dy * tr.y), f2bf(cur.z + dz * tr.z), f2bf(cur.w + dw * tr.w));
}

// ---------- final: out = x2 + sigmoid(rraw) * vout ----------
__global__ __launch_bounds__(256) void finalk(const float* __restrict__ x2,
    const float* __restrict__ rraw, const float* __restrict__ vout,
    float* __restrict__ out) {
  int idx4 = blockIdx.x * 256 + threadIdx.x;
  size_t off = ((size_t)idx4) << 2;
  float4 xv = *(const float4*)(x2 + off);
  float4 rv = *(const float4*)(rraw + off);
  float4 vv = *(const float4*)(vout + off);
  float4 o;
  o.x = xv.x + vv.x / (1.f + __expf(-rv.x));
  o.y = xv.y + vv.y / (1.f + __expf(-rv.y));
  o.z = xv.z + vv.z / (1.f + __expf(-rv.z));
  o.w = xv.w + vv.w / (1.f + __expf(-rv.w));
  *(float4*)(out + off) = o;
}

// ---------- host launcher ----------
extern "C" void kernel_launch(void* const* d_in, const int* in_sizes, int n_in,
                              void* d_out, int out_size, void* d_ws, size_t ws_size,
                              hipStream_t stream) {
  (void)in_sizes; (void)n_in; (void)out_size;
  const float* x        = (const float*)d_in[0];
  const float* in_proj  = (const float*)d_in[1];
  const float* conv_w   = (const float*)d_in[2];
  const float* conv_b   = (const float*)d_in[3];
  const float* dt_bias  = (const float*)d_in[4];
  const float* A_log    = (const float*)d_in[5];
  const float* Dvec     = (const float*)d_in[6];
  const float* mnorm_w  = (const float*)d_in[7];
  const float* out_proj = (const float*)d_in[8];
  const float* attn_w   = (const float*)d_in[9];
  const float* proj_w   = (const float*)d_in[10];
  const float* tmk      = (const float*)d_in[11];
  const float* tmr      = (const float*)d_in[12];
  const float* key_w    = (const float*)d_in[13];
  const float* recept_w = (const float*)d_in[14];
  const float* value_w  = (const float*)d_in[15];
  float* out = (float*)d_out;

  if (ws_size < 199229440ull) return;

  char* ws = (char*)d_ws;
  unsigned short* Wt   = (unsigned short*)(ws + 0);
  unsigned short* Abf  = (unsigned short*)(ws + 8912896ull);
  unsigned short* Abf2 = (unsigned short*)(ws + 42467328ull);
  float* bigF = (float*)(ws + 59244544ull);
  float* big1 = (float*)(ws + 95420416ull);
  float* big2 = (float*)(ws + 131072000ull);
  float* x1   = (float*)(ws + 164626432ull);
  float* xn3  = (float*)(ws + 181403648ull);
  float* dtb  = (float*)(ws + 198180864ull);
  float* labuf= (float*)(ws + 198705152ull);
  unsigned short* zbf  = Abf2;
  unsigned short* xkbf = Abf2;
  unsigned short* xrbf = Abf2 + 4194304;
  float* dhbuf = bigF;
  float* hseq  = (float*)Abf;

  dim3 b256(256);
  dim3 tb(32, 8);

  // ===== Phase A: mamba2 =====
  resrms_k<0, 0, 0><<<4096, b256, 0, stream>>>(x, nullptr, nullptr, Abf, nullptr);
  transp_k<<<dim3(64, 32), tb, 0, stream>>>(in_proj, Wt, 1024, 2048, 2048, 0, 4256);
  gemm4_k<1><<<512, b256, 0, stream>>>(Abf, Wt, zbf, 4096, 2048, 1024, 16);              // z (bf16)
  transp_k<<<dim3(72, 32), tb, 0, stream>>>(in_proj, Wt, 1024, 2208, 2304, 2048, 4256);
  gemm4_k<0><<<576, b256, 0, stream>>>(Abf, Wt, bigF, 4096, 2208, 1024, 18);             // xBC+dt (f32)
  dtk<<<512, b256, 0, stream>>>(bigF, dt_bias, dtb);
  convk<<<34816, b256, 0, stream>>>(bigF, conv_w, conv_b, big1);                         // xbc_act
  ssd1_k<<<2048, b256, 0, stream>>>(big1, dtb, A_log, big2, dhbuf, labuf);               // Y_intra, dh, la
  ssd2_k<<<2048, b256, 0, stream>>>(dhbuf, labuf, hseq);                                 // chunk states
  ssd3_k<<<2048, b256, 0, stream>>>(big1, hseq, labuf, Dvec, big2);                      // ydin final
  gnormk<<<4096, b256, 0, stream>>>(big2, zbf, mnorm_w, Abf);                            // g (bf16)
  transp_k<<<dim3(32, 64), tb, 0, stream>>>(out_proj, Wt, 2048, 1024, 1024, 0, 1024);
  gemm4_k<0><<<256, b256, 0, stream>>>(Abf, Wt, big1, 4096, 1024, 2048, 8);              // mo
  resrms_k<1, 1, 0><<<4096, b256, 0, stream>>>(x, big1, x1, Abf, nullptr);               // x1, xn2

  // ===== Phase B: mqa =====
  transp_k<<<dim3(36, 32), tb, 0, stream>>>(attn_w, Wt, 1024, 1152, 1152, 0, 1152);
  gemm4_k<0><<<288, b256, 0, stream>>>(Abf, Wt, big1, 4096, 1152, 1024, 9);              // qkv
  attnk<<<1024, b256, 0, stream>>>(big1, Abf);                                           // atty (bf16)
  transp_k<<<dim3(32, 32), tb, 0, stream>>>(proj_w, Wt, 1024, 1024, 1024, 0, 1024);
  gemm4_k<0><<<256, b256, 0, stream>>>(Abf, Wt, big2, 4096, 1024, 1024, 8);              // po
  resrms_k<1, 1, 1><<<4096, b256, 0, stream>>>(x1, big2, x1, Abf, xn3);                  // x2 (in x1), xn3

  // ===== Phase C: cmix =====
  mixk<<<4096, b256, 0, stream>>>(xn3, tmk, tmr, xkbf, xrbf);
  transp_k<<<dim3(128, 32), tb, 0, stream>>>(key_w, Wt, 1024, 4096, 4096, 0, 4096);
  gemm4_k<2><<<1024, b256, 0, stream>>>(xkbf, Wt, Abf, 4096, 4096, 1024, 32);            // kact (bf16)
  transp_k<<<dim3(32, 128), tb, 0, stream>>>(value_w, Wt, 4096, 1024, 1024, 0, 1024);
  gemm4_k<0><<<256, b256, 0, stream>>>(Abf, Wt, big2, 4096, 1024, 4096, 8);              // vout
  transp_k<<<dim3(32, 32), tb, 0, stream>>>(recept_w, Wt, 1024, 1024, 1024, 0, 1024);
  gemm4_k<0><<<256, b256, 0, stream>>>(xrbf, Wt, big1, 4096, 1024, 1024, 8);             // rraw
  finalk<<<4096, b256, 0, stream>>>(x1, big1, big2, out);
}

// Round 8
// 531.505 us; speedup vs baseline: 1.0141x; 1.0099x over previous
//
#include <hip/hip_runtime.h>

// ---------- helpers ----------
__device__ __forceinline__ unsigned short f2bf(float f) {
  unsigned u = __builtin_bit_cast(unsigned, f);
  u = u + 0x7fffu + ((u >> 16) & 1u);      // RNE
  return (unsigned short)(u >> 16);
}
__device__ __forceinline__ float bf2f(unsigned short u) {
  return __builtin_bit_cast(float, ((unsigned)u) << 16);
}

typedef __bf16 bf16x8 __attribute__((ext_vector_type(8)));
typedef float  f32x4  __attribute__((ext_vector_type(4)));
typedef unsigned short u16x8 __attribute__((ext_vector_type(8)));

#define GLD16(gp, lp) __builtin_amdgcn_global_load_lds( \
    (const __attribute__((address_space(1))) unsigned int*)(gp), \
    (__attribute__((address_space(3))) unsigned int*)(lp), 16, 0, 0)

// ---------- rmsnorm (+ optional residual) ----------
template<int HAS_DELTA, int WRITE_SUM, int WRITE_N32>
__global__ __launch_bounds__(256) void resrms_k(const float* __restrict__ xin,
    const float* __restrict__ delta, float* __restrict__ xsum,
    unsigned short* __restrict__ nbf, float* __restrict__ nf32) {
  int row = blockIdx.x, tid = threadIdx.x;
  size_t base = ((size_t)row << 10) + ((size_t)tid << 2);
  float4 v = *(const float4*)(xin + base);
  if (HAS_DELTA) {
    float4 d = *(const float4*)(delta + base);
    v.x += d.x; v.y += d.y; v.z += d.z; v.w += d.w;
  }
  if (WRITE_SUM) *(float4*)(xsum + base) = v;
  float ss = v.x*v.x + v.y*v.y + v.z*v.z + v.w*v.w;
  #pragma unroll
  for (int off = 32; off; off >>= 1) ss += __shfl_xor(ss, off);
  __shared__ float ws4[4];
  if ((tid & 63) == 0) ws4[tid >> 6] = ss;
  __syncthreads();
  float tot = ws4[0] + ws4[1] + ws4[2] + ws4[3];
  float sc = rsqrtf(tot * (1.0f / 1024.0f) + 1e-5f);
  *(ushort4*)(nbf + base) = make_ushort4(f2bf(v.x*sc), f2bf(v.y*sc), f2bf(v.z*sc), f2bf(v.w*sc));
  if (WRITE_N32) {
    float4 n; n.x = v.x*sc; n.y = v.y*sc; n.z = v.z*sc; n.w = v.w*sc;
    *(float4*)(nf32 + base) = n;
  }
}

// ---------- transpose+convert: W[K][ldw] f32 -> Wt[Npad][K] bf16 ----------
__global__ void transp_k(const float* __restrict__ W, unsigned short* __restrict__ Wt,
                         int K, int Ncols, int Npad, int col_off, int ldw) {
  __shared__ float t[32][33];
  int n0 = blockIdx.x << 5, k0 = blockIdx.y << 5;
  int tx = threadIdx.x, ty = threadIdx.y;
  #pragma unroll
  for (int rr = 0; rr < 32; rr += 8) {
    int k = k0 + rr + ty, n = n0 + tx;
    t[rr + ty][tx] = (n < Ncols) ? W[(size_t)k * ldw + col_off + n] : 0.f;
  }
  __syncthreads();
  #pragma unroll
  for (int rr = 0; rr < 32; rr += 8) {
    int nrow = n0 + rr + ty;
    Wt[(size_t)nrow * K + k0 + tx] = f2bf(t[tx][rr + ty]);
  }
}

// ---------- bf16 MFMA GEMM (m97-class, 3 blk/CU): C[M][N] = A[M][K] * Bt[N][K]^T ----------
// BM=BN=128, BK=32, 256 threads = 4 waves (2Mx2N), wave tile 64x64, acc 4x4.
// 3 rotating LDS buffers (16KB each), prefetch distance 2, counted vmcnt(4), raw barriers.
// Chunk-XOR swizzle: phys = c ^ ((row>>1)&3), applied both sides (2-way = free).
// XCD swizzle with 2D stripe (S | ntx) for L2 working-set compaction.
// Epilogue through LDS: contiguous 16B per-lane stores, no C-line RMW.
// EPI: 0 = f32 store, 1 = bf16 store, 2 = erf-activation -> bf16 store
template<int EPI>
__global__ __launch_bounds__(256, 3) void gemm4_k(const unsigned short* __restrict__ A,
    const unsigned short* __restrict__ Bt, void* __restrict__ Cout,
    int M, int N, int K, int ntx) {
  __shared__ char smem[49152];            // 3 x (A 8KB + B 8KB); epilogue reuses 33.8KB
  unsigned short* lds = (unsigned short*)smem;
  const int tid = threadIdx.x;
  const int w = tid >> 6, lane = tid & 63;
  const int fr = lane & 15, g = lane >> 4;
  // XCD-aware bijective block swizzle + 2D stripe within XCD chunk
  const int nwg = gridDim.x;
  const int nty = nwg / ntx;
  const int l = (blockIdx.x & 7) * (nwg >> 3) + (blockIdx.x >> 3);
  const int S = ((ntx & 3) == 0) ? 4 : (((ntx & 1) == 0) ? 2 : 1);
  const int sw = S * nty;
  const int s = l / sw, r_ = l - s * sw;
  const int bx = s * S + (r_ % S);
  const int by = r_ / S;
  const int m0 = by << 7, n0 = bx << 7;
  const int wm = (w >> 1) << 6, wn = (w & 1) << 6;

  f32x4 acc[4][4];
  #pragma unroll
  for (int i = 0; i < 4; ++i)
    #pragma unroll
    for (int j = 0; j < 4; ++j) acc[i][j] = (f32x4){0.f, 0.f, 0.f, 0.f};

  // staging: slot s in {tid, tid+256}; row=s>>2, phys chunk=s&3, logical=phys^((row>>1)&3)
  const int r0s = tid >> 2, pc0 = tid & 3;
  const int lc0 = pc0 ^ ((r0s >> 1) & 3);
  const int r1s = r0s + 64;
  const int lc1 = pc0 ^ ((r1s >> 1) & 3);
  const unsigned short* a0 = A + (size_t)(m0 + r0s) * K + (lc0 << 3);
  const unsigned short* a1 = A + (size_t)(m0 + r1s) * K + (lc1 << 3);
  const unsigned short* b0 = Bt + (size_t)(n0 + r0s) * K + (lc0 << 3);
  const unsigned short* b1 = Bt + (size_t)(n0 + r1s) * K + (lc1 << 3);
  const int wofs = w << 9;   // wave slot: 64 lanes x 8 shorts = 512 shorts per wave per instr

#define STAGE4(kt_, bb_) { \
    unsigned short* d_ = lds + (bb_) * 8192 + wofs; \
    GLD16(a0 + ((kt_) << 5), d_); \
    GLD16(a1 + ((kt_) << 5), d_ + 2048); \
    GLD16(b0 + ((kt_) << 5), d_ + 4096); \
    GLD16(b1 + ((kt_) << 5), d_ + 6144); }

  const int NT = K >> 5;
  STAGE4(0, 0)
  STAGE4(1, 1)
  asm volatile("s_waitcnt vmcnt(4)" ::: "memory");
  __builtin_amdgcn_s_barrier();
  __builtin_amdgcn_sched_barrier(0);

  int cb = 0;
  for (int t = 0; t < NT; ++t) {
    const unsigned short* bufp = lds + cb * 8192;
    int sb = cb + 2; if (sb >= 3) sb -= 3;
    const int have2 = (t + 2 < NT);
    if (have2) STAGE4(t + 2, sb)
    bf16x8 af[4], bv[4];
    #pragma unroll
    for (int i = 0; i < 4; ++i) {
      int r = wm + (i << 4) + fr;
      af[i] = *(const bf16x8*)&bufp[(r << 5) + (((g ^ (r >> 1)) & 3) << 3)];
    }
    #pragma unroll
    for (int j = 0; j < 4; ++j) {
      int r = wn + (j << 4) + fr;
      bv[j] = *(const bf16x8*)&bufp[4096 + (r << 5) + (((g ^ (r >> 1)) & 3) << 3)];
    }
    __builtin_amdgcn_s_setprio(1);
    #pragma unroll
    for (int i = 0; i < 4; ++i)
      #pragma unroll
      for (int j = 0; j < 4; ++j)
        acc[i][j] = __builtin_amdgcn_mfma_f32_16x16x32_bf16(af[i], bv[j], acc[i][j], 0, 0, 0);
    __builtin_amdgcn_s_setprio(0);
    if (t + 1 < NT) {
      if (have2) { asm volatile("s_waitcnt vmcnt(4)" ::: "memory"); }
      else       { asm volatile("s_waitcnt vmcnt(0)" ::: "memory"); }
      __builtin_amdgcn_s_barrier();
      __builtin_amdgcn_sched_barrier(0);
    }
    cb = cb + 1; if (cb >= 3) cb -= 3;
  }
#undef STAGE4

  // ---- epilogue via LDS: contiguous 16B stores ----
  float (*eps)[132] = (float(*)[132])smem;   // 64 x 132 f32 = 33792B
  const int rin = g << 2;
  const int er = tid >> 2, ec0 = (tid & 3) << 5;
  #pragma unroll
  for (int rh = 0; rh < 2; ++rh) {
    __syncthreads();
    if ((wm >> 6) == rh) {
      #pragma unroll
      for (int i = 0; i < 4; ++i)
        #pragma unroll
        for (int j = 0; j < 4; ++j)
          #pragma unroll
          for (int rr = 0; rr < 4; ++rr)
            eps[(i << 4) + rin + rr][wn + (j << 4) + fr] = acc[i][j][rr];
    }
    __syncthreads();
    int grow = m0 + (rh << 6) + er;
    if (EPI == 0) {
      float* orow = (float*)Cout + (size_t)grow * N + n0 + ec0;
      #pragma unroll
      for (int u = 0; u < 8; ++u) {
        int col = n0 + ec0 + (u << 2);
        if (col < N) {
          float4 v; v.x = eps[er][ec0 + (u<<2)]; v.y = eps[er][ec0 + (u<<2) + 1];
          v.z = eps[er][ec0 + (u<<2) + 2]; v.w = eps[er][ec0 + (u<<2) + 3];
          *(float4*)(orow + (u << 2)) = v;
        }
      }
    } else {
      unsigned short* orow = (unsigned short*)Cout + (size_t)grow * N + n0 + ec0;
      #pragma unroll
      for (int u = 0; u < 4; ++u) {
        int col = n0 + ec0 + (u << 3);
        if (col < N) {
          u16x8 pk;
          #pragma unroll
          for (int e = 0; e < 8; ++e) {
            float v = eps[er][ec0 + (u << 3) + e];
            if (EPI == 2) v = 0.5f * (1.0f + erff((v - 0.70710678f) * 2.5066283f));
            pk[e] = f2bf(v);
          }
          *(u16x8*)(orow + (u << 3)) = pk;
        }
      }
    }
  }
}

// ---------- causal depthwise conv(4) + silu, with fused dt/softplus ----------
__global__ __launch_bounds__(256) void convk(const float* __restrict__ zxr,
    const float* __restrict__ conv_w, const float* __restrict__ conv_b,
    const float* __restrict__ dt_bias, float* __restrict__ xbc,
    float* __restrict__ dtb) {
  int i = blockIdx.x * 256 + threadIdx.x;     // 4*1024*2176
  if (i >= 4 * 1024 * 2176) return;
  int c = i % 2176; int bt = i / 2176; int t = bt & 1023;
  const float* col = zxr + (size_t)bt * 2208 + c;
  float acc = conv_b[c];
  float w0 = conv_w[c * 4 + 0], w1 = conv_w[c * 4 + 1], w2 = conv_w[c * 4 + 2], w3 = conv_w[c * 4 + 3];
  if (t >= 3) acc = fmaf(col[-3 * 2208], w0, acc);
  if (t >= 2) acc = fmaf(col[-2 * 2208], w1, acc);
  if (t >= 1) acc = fmaf(col[-1 * 2208], w2, acc);
  acc = fmaf(col[0], w3, acc);
  xbc[(size_t)bt * 2176 + c] = acc / (1.f + __expf(-acc));
  if (c < 32) {
    float v = zxr[(size_t)bt * 2208 + 2176 + c] + dt_bias[c];
    dtb[bt * 32 + c] = (v > 20.f) ? v : log1pf(__expf(v));
  }
}

// ---------- SSD chunked scan, stage 1 ----------
__global__ __launch_bounds__(256) void ssd1_k(const float* __restrict__ xbc,
    const float* __restrict__ dtb, const float* __restrict__ A_log,
    float* __restrict__ ydin, float* __restrict__ dhbuf, float* __restrict__ labuf) {
  __shared__ unsigned short Cs[64][68];   // [t][d]
  __shared__ unsigned short Bsm[64][68];  // [s][d]
  __shared__ unsigned short XT[64][68];   // [p][s]
  __shared__ unsigned short BT[64][68];   // [n][s] (scaled)
  __shared__ unsigned short Ms[64][68];   // [t][s]
  __shared__ float laS[64], dtS[64];
  const int id = blockIdx.x;
  const int h = id & 31, b = (id >> 5) & 3, c = id >> 7;
  const int tid = threadIdx.x, w = tid >> 6, lane = tid & 63;
  const int fr = lane & 15, g = lane >> 4;
  const size_t rowbase = (size_t)((b << 10) + (c << 6));

  {
    int r = tid >> 2, c0 = (tid & 3) << 4;
    const float* src = xbc + (rowbase + r) * 2176;
    #pragma unroll
    for (int i = 0; i < 4; ++i) {
      float4 v = *(const float4*)(src + 2112 + c0 + 4 * i);
      *(ushort4*)&Cs[r][c0 + 4 * i] = make_ushort4(f2bf(v.x), f2bf(v.y), f2bf(v.z), f2bf(v.w));
      float4 u = *(const float4*)(src + 2048 + c0 + 4 * i);
      *(ushort4*)&Bsm[r][c0 + 4 * i] = make_ushort4(f2bf(u.x), f2bf(u.y), f2bf(u.z), f2bf(u.w));
    }
  }
  {
    int r0 = (tid & 15) << 2, d0 = (tid >> 4) << 2;
    const float* src = xbc + (rowbase + r0) * 2176 + (h << 6) + d0;
    float4 v0 = *(const float4*)(src);
    float4 v1 = *(const float4*)(src + 2176);
    float4 v2 = *(const float4*)(src + 4352);
    float4 v3 = *(const float4*)(src + 6528);
    *(ushort4*)&XT[d0 + 0][r0] = make_ushort4(f2bf(v0.x), f2bf(v1.x), f2bf(v2.x), f2bf(v3.x));
    *(ushort4*)&XT[d0 + 1][r0] = make_ushort4(f2bf(v0.y), f2bf(v1.y), f2bf(v2.y), f2bf(v3.y));
    *(ushort4*)&XT[d0 + 2][r0] = make_ushort4(f2bf(v0.z), f2bf(v1.z), f2bf(v2.z), f2bf(v3.z));
    *(ushort4*)&XT[d0 + 3][r0] = make_ushort4(f2bf(v0.w), f2bf(v1.w), f2bf(v2.w), f2bf(v3.w));
  }
  if (w == 0) {
    float Ah = -__expf(A_log[h]);
    float dtv = dtb[(rowbase + lane) * 32 + h];
    float v = dtv * Ah;
    #pragma unroll
    for (int off = 1; off < 64; off <<= 1) {
      float u = __shfl_up(v, off);
      if (lane >= off) v += u;
    }
    laS[lane] = v; dtS[lane] = dtv;
    labuf[(size_t)((((b << 4) | c) << 5 | h) << 6) + lane] = v;
  }
  __syncthreads();

  const int wr = w >> 1, wc = w & 1;
  f32x4 gf[2][2];
  #pragma unroll
  for (int i = 0; i < 2; ++i)
    #pragma unroll
    for (int j = 0; j < 2; ++j) gf[i][j] = (f32x4){0.f, 0.f, 0.f, 0.f};
  {
    int r0 = (tid & 15) << 2, d0 = (tid >> 4) << 2;
    const float* src = xbc + (rowbase + r0) * 2176 + 2048 + d0;
    float la63 = laS[63];
    float4 v0 = *(const float4*)(src);
    float4 v1 = *(const float4*)(src + 2176);
    float4 v2 = *(const float4*)(src + 4352);
    float4 v3 = *(const float4*)(src + 6528);
    float w0 = __expf(la63 - laS[r0 + 0]) * dtS[r0 + 0];
    float w1 = __expf(la63 - laS[r0 + 1]) * dtS[r0 + 1];
    float w2 = __expf(la63 - laS[r0 + 2]) * dtS[r0 + 2];
    float w3 = __expf(la63 - laS[r0 + 3]) * dtS[r0 + 3];
    *(ushort4*)&BT[d0 + 0][r0] = make_ushort4(f2bf(v0.x*w0), f2bf(v1.x*w1), f2bf(v2.x*w2), f2bf(v3.x*w3));
    *(ushort4*)&BT[d0 + 1][r0] = make_ushort4(f2bf(v0.y*w0), f2bf(v1.y*w1), f2bf(v2.y*w2), f2bf(v3.y*w3));
    *(ushort4*)&BT[d0 + 2][r0] = make_ushort4(f2bf(v0.z*w0), f2bf(v1.z*w1), f2bf(v2.z*w2), f2bf(v3.z*w3));
    *(ushort4*)&BT[d0 + 3][r0] = make_ushort4(f2bf(v0.w*w0), f2bf(v1.w*w1), f2bf(v2.w*w2), f2bf(v3.w*w3));
  }
  #pragma unroll
  for (int ks = 0; ks < 2; ++ks) {
    bf16x8 ca[2], bb[2];
    #pragma unroll
    for (int i = 0; i < 2; ++i) ca[i] = *(const bf16x8*)&Cs[(wr << 5) + (i << 4) + fr][(ks << 5) + (g << 3)];
    #pragma unroll
    for (int j = 0; j < 2; ++j) bb[j] = *(const bf16x8*)&Bsm[(wc << 5) + (j << 4) + fr][(ks << 5) + (g << 3)];
    #pragma unroll
    for (int i = 0; i < 2; ++i)
      #pragma unroll
      for (int j = 0; j < 2; ++j)
        gf[i][j] = __builtin_amdgcn_mfma_f32_16x16x32_bf16(ca[i], bb[j], gf[i][j], 0, 0, 0);
  }
  #pragma unroll
  for (int i = 0; i < 2; ++i) {
    #pragma unroll
    for (int j = 0; j < 2; ++j) {
      int s = (wc << 5) + (j << 4) + fr;
      float la_s = laS[s], dt_s = dtS[s];
      #pragma unroll
      for (int rr = 0; rr < 4; ++rr) {
        int t = (wr << 5) + (i << 4) + (g << 2) + rr;
        float e = __expf(fminf(laS[t] - la_s, 0.f));
        float val = (s <= t) ? gf[i][j][rr] * e * dt_s : 0.f;
        Ms[t][s] = f2bf(val);
      }
    }
  }
  __syncthreads();

  f32x4 yf[2][2], hf[2][2];
  #pragma unroll
  for (int i = 0; i < 2; ++i)
    #pragma unroll
    for (int j = 0; j < 2; ++j) { yf[i][j] = (f32x4){0.f,0.f,0.f,0.f}; hf[i][j] = (f32x4){0.f,0.f,0.f,0.f}; }
  #pragma unroll
  for (int ks = 0; ks < 2; ++ks) {
    bf16x8 ma[2], ba[2], xb[2];
    #pragma unroll
    for (int i = 0; i < 2; ++i) {
      ma[i] = *(const bf16x8*)&Ms[(wr << 5) + (i << 4) + fr][(ks << 5) + (g << 3)];
      ba[i] = *(const bf16x8*)&BT[(wr << 5) + (i << 4) + fr][(ks << 5) + (g << 3)];
    }
    #pragma unroll
    for (int j = 0; j < 2; ++j) xb[j] = *(const bf16x8*)&XT[(wc << 5) + (j << 4) + fr][(ks << 5) + (g << 3)];
    #pragma unroll
    for (int i = 0; i < 2; ++i)
      #pragma unroll
      for (int j = 0; j < 2; ++j) {
        yf[i][j] = __builtin_amdgcn_mfma_f32_16x16x32_bf16(ma[i], xb[j], yf[i][j], 0, 0, 0);
        hf[i][j] = __builtin_amdgcn_mfma_f32_16x16x32_bf16(ba[i], xb[j], hf[i][j], 0, 0, 0);
      }
  }
  float* dhb = dhbuf + ((size_t)(((c << 2) + b) * 32 + h) << 12);
  #pragma unroll
  for (int i = 0; i < 2; ++i) {
    #pragma unroll
    for (int j = 0; j < 2; ++j) {
      int p = (wc << 5) + (j << 4) + fr;
      #pragma unroll
      for (int rr = 0; rr < 4; ++rr) {
        int t = (wr << 5) + (i << 4) + (g << 2) + rr;
        ydin[((rowbase + t) << 11) + (h << 6) + p] = yf[i][j][rr];
        dhb[(t << 6) + p] = hf[i][j][rr];
      }
    }
  }
}

// ---------- SSD stage 2 ----------
__global__ __launch_bounds__(256) void ssd2_k(const float* __restrict__ dhbuf,
    const float* __restrict__ labuf, float* __restrict__ hseq) {
  int idx = blockIdx.x * 256 + threadIdx.x;   // 524288 = b*h*n*p
  int np = idx & 4095;
  int h = (idx >> 12) & 31, b = idx >> 17;
  float carry = 0.f;
  #pragma unroll
  for (int c = 0; c < 16; ++c) {
    size_t o = ((size_t)(((c << 2) + b) * 32 + h) << 12) + np;
    hseq[o] = carry;
    float ec = __expf(labuf[(size_t)((((b << 4) | c) << 5 | h) << 6) + 63]);
    carry = fmaf(ec, carry, dhbuf[o]);
  }
}

// ---------- SSD stage 3 ----------
__global__ __launch_bounds__(256) void ssd3_k(const float* __restrict__ xbc,
    const float* __restrict__ hseq, const float* __restrict__ labuf,
    const float* __restrict__ Dv, float* __restrict__ ydin) {
  __shared__ unsigned short Cs[64][68];
  __shared__ unsigned short HT[64][68];
  __shared__ float laS[64];
  const int id = blockIdx.x;
  const int h = id & 31, b = (id >> 5) & 3, c = id >> 7;
  const int tid = threadIdx.x, w = tid >> 6, lane = tid & 63;
  const int fr = lane & 15, g = lane >> 4;
  const size_t rowbase = (size_t)((b << 10) + (c << 6));
  {
    int r = tid >> 2, c0 = (tid & 3) << 4;
    const float* src = xbc + (rowbase + r) * 2176 + 2112 + c0;
    #pragma unroll
    for (int i = 0; i < 4; ++i) {
      float4 v = *(const float4*)(src + 4 * i);
      *(ushort4*)&Cs[r][c0 + 4 * i] = make_ushort4(f2bf(v.x), f2bf(v.y), f2bf(v.z), f2bf(v.w));
    }
  }
  {
    const float* hb = hseq + ((size_t)(((c << 2) + b) * 32 + h) << 12);
    int n0 = (tid & 15) << 2, p0 = (tid >> 4) << 2;
    float4 v0 = *(const float4*)(hb + ((n0 + 0) << 6) + p0);
    float4 v1 = *(const float4*)(hb + ((n0 + 1) << 6) + p0);
    float4 v2 = *(const float4*)(hb + ((n0 + 2) << 6) + p0);
    float4 v3 = *(const float4*)(hb + ((n0 + 3) << 6) + p0);
    *(ushort4*)&HT[p0 + 0][n0] = make_ushort4(f2bf(v0.x), f2bf(v1.x), f2bf(v2.x), f2bf(v3.x));
    *(ushort4*)&HT[p0 + 1][n0] = make_ushort4(f2bf(v0.y), f2bf(v1.y), f2bf(v2.y), f2bf(v3.y));
    *(ushort4*)&HT[p0 + 2][n0] = make_ushort4(f2bf(v0.z), f2bf(v1.z), f2bf(v2.z), f2bf(v3.z));
    *(ushort4*)&HT[p0 + 3][n0] = make_ushort4(f2bf(v0.w), f2bf(v1.w), f2bf(v2.w), f2bf(v3.w));
  }
  if (tid < 64) laS[tid] = labuf[(size_t)((((b << 4) | c) << 5 | h) << 6) + tid];
  __syncthreads();
  const int wr = w >> 1, wc = w & 1;
  f32x4 yf[2][2];
  #pragma unroll
  for (int i = 0; i < 2; ++i)
    #pragma unroll
    for (int j = 0; j < 2; ++j) yf[i][j] = (f32x4){0.f, 0.f, 0.f, 0.f};
  #pragma unroll
  for (int ks = 0; ks < 2; ++ks) {
    bf16x8 ca[2], hv[2];
    #pragma unroll
    for (int i = 0; i < 2; ++i) ca[i] = *(const bf16x8*)&Cs[(wr << 5) + (i << 4) + fr][(ks << 5) + (g << 3)];
    #pragma unroll
    for (int j = 0; j < 2; ++j) hv[j] = *(const bf16x8*)&HT[(wc << 5) + (j << 4) + fr][(ks << 5) + (g << 3)];
    #pragma unroll
    for (int i = 0; i < 2; ++i)
      #pragma unroll
      for (int j = 0; j < 2; ++j)
        yf[i][j] = __builtin_amdgcn_mfma_f32_16x16x32_bf16(ca[i], hv[j], yf[i][j], 0, 0, 0);
  }
  float Dh = Dv[h];
  #pragma unroll
  for (int i = 0; i < 2; ++i) {
    #pragma unroll
    for (int j = 0; j < 2; ++j) {
      int p = (wc << 5) + (j << 4) + fr;
      #pragma unroll
      for (int rr = 0; rr < 4; ++rr) {
        int t = (wr << 5) + (i << 4) + (g << 2) + rr;
        size_t yo = ((rowbase + t) << 11) + (h << 6) + p;
        float xv = xbc[(rowbase + t) * 2176 + (h << 6) + p];
        ydin[yo] = ydin[yo] + __expf(laS[t]) * yf[i][j][rr] + Dh * xv;
      }
    }
  }
}

// ---------- g = ydin * silu(z); rmsnorm(2048) * mnorm_w -> bf16 ----------
__global__ __launch_bounds__(256) void gnormk(const float* __restrict__ ydin,
    const unsigned short* __restrict__ zbf, const float* __restrict__ mw,
    unsigned short* __restrict__ gbf) {
  int row = blockIdx.x, tid = threadIdx.x;
  size_t base = ((size_t)row << 11) + ((size_t)tid << 3);
  float4 y0 = *(const float4*)(ydin + base);
  float4 y1 = *(const float4*)(ydin + base + 4);
  ushort4 z0 = *(const ushort4*)(zbf + base);
  ushort4 z1 = *(const ushort4*)(zbf + base + 4);
  float g[8];
  {
    float z;
    z = bf2f(z0.x); g[0] = y0.x * (z / (1.f + __expf(-z)));
    z = bf2f(z0.y); g[1] = y0.y * (z / (1.f + __expf(-z)));
    z = bf2f(z0.z); g[2] = y0.z * (z / (1.f + __expf(-z)));
    z = bf2f(z0.w); g[3] = y0.w * (z / (1.f + __expf(-z)));
    z = bf2f(z1.x); g[4] = y1.x * (z / (1.f + __expf(-z)));
    z = bf2f(z1.y); g[5] = y1.y * (z / (1.f + __expf(-z)));
    z = bf2f(z1.z); g[6] = y1.z * (z / (1.f + __expf(-z)));
    z = bf2f(z1.w); g[7] = y1.w * (z / (1.f + __expf(-z)));
  }
  float ss = 0.f;
  #pragma unroll
  for (int k = 0; k < 8; ++k) ss += g[k] * g[k];
  #pragma unroll
  for (int off = 32; off; off >>= 1) ss += __shfl_xor(ss, off);
  __shared__ float ws4[4];
  if ((tid & 63) == 0) ws4[tid >> 6] = ss;
  __syncthreads();
  float tot = ws4[0] + ws4[1] + ws4[2] + ws4[3];
  float sc = rsqrtf(tot * (1.f / 2048.f) + 1e-5f);
  int c0 = tid << 3;
  float4 m0 = *(const float4*)(mw + c0);
  float4 m1 = *(const float4*)(mw + c0 + 4);
  *(ushort4*)(gbf + base)     = make_ushort4(f2bf(g[0]*sc*m0.x), f2bf(g[1]*sc*m0.y), f2bf(g[2]*sc*m0.z), f2bf(g[3]*sc*m0.w));
  *(ushort4*)(gbf + base + 4) = make_ushort4(f2bf(g[4]*sc*m1.x), f2bf(g[5]*sc*m1.y), f2bf(g[6]*sc*m1.z), f2bf(g[7]*sc*m1.w));
}

// ---------- MQA causal attention (MFMA flash), bf16 in/out ----------
__global__ __launch_bounds__(256) void attnk(const unsigned short* __restrict__ qkv,
                                             unsigned short* __restrict__ ybf) {
  __shared__ unsigned short Qs[64][72];
  __shared__ unsigned short Ks[64][72];
  __shared__ unsigned short VT[64][72];
  __shared__ unsigned short Ps[4][16][72];
  const int id = blockIdx.x;
  const int b = id & 3, h = (id >> 2) & 15, qt = id >> 6;
  const int t0 = qt << 6;
  const int tid = threadIdx.x, w = tid >> 6, lane = tid & 63;
  const int fr = lane & 15, g = lane >> 4;
  {
    int r = tid >> 2, d0 = (tid & 3) << 4;
    const unsigned short* src = qkv + ((size_t)((b << 10) | (t0 + r))) * 1152 + (h << 6) + d0;
    *(uint4*)&Qs[r][d0]     = *(const uint4*)(src);
    *(uint4*)&Qs[r][d0 + 8] = *(const uint4*)(src + 8);
  }
  __syncthreads();
  bf16x8 afQ0 = *(const bf16x8*)&Qs[(w << 4) + fr][g << 3];
  bf16x8 afQ1 = *(const bf16x8*)&Qs[(w << 4) + fr][32 + (g << 3)];
  f32x4 acc_o[4];
  #pragma unroll
  for (int i = 0; i < 4; ++i) acc_o[i] = (f32x4){0.f, 0.f, 0.f, 0.f};
  float m[4] = {-1e30f, -1e30f, -1e30f, -1e30f};
  float l[4] = {0.f, 0.f, 0.f, 0.f};
  const int qrow = t0 + (w << 4) + (g << 2);
  for (int kt = 0; kt <= qt; ++kt) {
    const int s0 = kt << 6;
    __syncthreads();
    {
      int r = tid >> 2, d0 = (tid & 3) << 4;
      const unsigned short* src = qkv + ((size_t)((b << 10) | (s0 + r))) * 1152 + 1024 + d0;
      *(uint4*)&Ks[r][d0]     = *(const uint4*)(src);
      *(uint4*)&Ks[r][d0 + 8] = *(const uint4*)(src + 8);
    }
    {
      int r0 = (tid & 15) << 2, d0 = (tid >> 4) << 2;
      const unsigned short* src = qkv + ((size_t)((b << 10) | (s0 + r0))) * 1152 + 1088 + d0;
      ushort4 v0 = *(const ushort4*)(src);
      ushort4 v1 = *(const ushort4*)(src + 1152);
      ushort4 v2 = *(const ushort4*)(src + 2304);
      ushort4 v3 = *(const ushort4*)(src + 3456);
      *(ushort4*)&VT[d0 + 0][r0] = make_ushort4(v0.x, v1.x, v2.x, v3.x);
      *(ushort4*)&VT[d0 + 1][r0] = make_ushort4(v0.y, v1.y, v2.y, v3.y);
      *(ushort4*)&VT[d0 + 2][r0] = make_ushort4(v0.z, v1.z, v2.z, v3.z);
      *(ushort4*)&VT[d0 + 3][r0] = make_ushort4(v0.w, v1.w, v2.w, v3.w);
    }
    __syncthreads();
    f32x4 s4[4];
    #pragma unroll
    for (int jt = 0; jt < 4; ++jt) {
      bf16x8 b0 = *(const bf16x8*)&Ks[(jt << 4) + fr][g << 3];
      bf16x8 b1 = *(const bf16x8*)&Ks[(jt << 4) + fr][32 + (g << 3)];
      f32x4 z4 = (f32x4){0.f, 0.f, 0.f, 0.f};
      z4 = __builtin_amdgcn_mfma_f32_16x16x32_bf16(afQ0, b0, z4, 0, 0, 0);
      z4 = __builtin_amdgcn_mfma_f32_16x16x32_bf16(afQ1, b1, z4, 0, 0, 0);
      s4[jt] = z4 * 0.125f;   // fold 1/sqrt(64) here instead of scaling Q
    }
    if (kt == qt) {
      #pragma unroll
      for (int jt = 0; jt < 4; ++jt) {
        int key = s0 + (jt << 4) + fr;
        #pragma unroll
        for (int r = 0; r < 4; ++r)
          if (key > qrow + r) s4[jt][r] = -1e30f;
      }
    }
    #pragma unroll
    for (int r = 0; r < 4; ++r) {
      float mt = fmaxf(fmaxf(s4[0][r], s4[1][r]), fmaxf(s4[2][r], s4[3][r]));
      #pragma unroll
      for (int off = 8; off; off >>= 1) mt = fmaxf(mt, __shfl_xor(mt, off));
      float mn = fmaxf(m[r], mt);
      float scl = __expf(m[r] - mn);
      m[r] = mn;
      float ps = 0.f;
      #pragma unroll
      for (int jt = 0; jt < 4; ++jt) {
        float p = __expf(s4[jt][r] - mn);
        ps += p;
        Ps[w][(g << 2) + r][(jt << 4) + fr] = f2bf(p);
      }
      #pragma unroll
      for (int off = 8; off; off >>= 1) ps += __shfl_xor(ps, off);
      l[r] = l[r] * scl + ps;
      acc_o[0][r] *= scl; acc_o[1][r] *= scl; acc_o[2][r] *= scl; acc_o[3][r] *= scl;
    }
    #pragma unroll
    for (int ks = 0; ks < 2; ++ks) {
      bf16x8 ap = *(const bf16x8*)&Ps[w][fr][(ks << 5) + (g << 3)];
      #pragma unroll
      for (int dt = 0; dt < 4; ++dt) {
        bf16x8 bv = *(const bf16x8*)&VT[(dt << 4) + fr][(ks << 5) + (g << 3)];
        acc_o[dt] = __builtin_amdgcn_mfma_f32_16x16x32_bf16(ap, bv, acc_o[dt], 0, 0, 0);
      }
    }
  }
  #pragma unroll
  for (int dt = 0; dt < 4; ++dt) {
    #pragma unroll
    for (int r = 0; r < 4; ++r) {
      float o = acc_o[dt][r] / l[r];
      int t = t0 + (w << 4) + (g << 2) + r;
      ybf[(((size_t)((b << 10) | t)) << 10) + (h << 6) + (dt << 4) + fr] = f2bf(o);
    }
  }
}

// ---------- cmix token-shift mix -> xk, xr (bf16) ----------
__global__ __launch_bounds__(256) void mixk(const float* __restrict__ xn3,
    const float* __restrict__ tmk, const float* __restrict__ tmr,
    unsigned short* __restrict__ xkbf, unsigned short* __restrict__ xrbf) {
  int idx4 = blockIdx.x * 256 + threadIdx.x;
  int col = (idx4 & 255) << 2;
  int row = idx4 >> 8;
  int t = row & 1023;
  size_t off = ((size_t)idx4) << 2;
  float4 cur = *(const float4*)(xn3 + off);
  float4 prev = make_float4(0.f, 0.f, 0.f, 0.f);
  if (t > 0) prev = *(const float4*)(xn3 + off - 1024);
  float4 tk = *(const float4*)(tmk + col);
  float4 tr = *(const float4*)(tmr + col);
  float dx = prev.x - cur.x, dy = prev.y - cur.y, dz = prev.z - cur.z, dw = prev.w - cur.w;
  *(ushort4*)(xkbf + off) = make_ushort4(
      f2bf(cur.x + dx * tk.x), f2bf(cur.y + dy * tk.y), f2bf(cur.z + dz * tk.z), f2bf(cur.w + dw * tk.w));
  *(ushort4*)(xrbf + off) = make_ushort4(
      f2bf(cur.x + dx * tr.x), f2bf(cur.y + dy * tr.y), f2bf(cur.z + dz * tr.z), f2bf(cur.w + dw * tr.w));
}

// ---------- final: out = x2 + sigmoid(rraw) * vout ----------
__global__ __launch_bounds__(256) void finalk(const float* __restrict__ x2,
    const float* __restrict__ rraw, const float* __restrict__ vout,
    float* __restrict__ out) {
  int idx4 = blockIdx.x * 256 + threadIdx.x;
  size_t off = ((size_t)idx4) << 2;
  float4 xv = *(const float4*)(x2 + off);
  float4 rv = *(const float4*)(rraw + off);
  float4 vv = *(const float4*)(vout + off);
  float4 o;
  o.x = xv.x + vv.x / (1.f + __expf(-rv.x));
  o.y = xv.y + vv.y / (1.f + __expf(-rv.y));
  o.z = xv.z + vv.z / (1.f + __expf(-rv.z));
  o.w = xv.w + vv.w / (1.f + __expf(-rv.w));
  *(float4*)(out + off) = o;
}

// ---------- host launcher ----------
extern "C" void kernel_launch(void* const* d_in, const int* in_sizes, int n_in,
                              void* d_out, int out_size, void* d_ws, size_t ws_size,
                              hipStream_t stream) {
  (void)in_sizes; (void)n_in; (void)out_size;
  const float* x        = (const float*)d_in[0];
  const float* in_proj  = (const float*)d_in[1];
  const float* conv_w   = (const float*)d_in[2];
  const float* conv_b   = (const float*)d_in[3];
  const float* dt_bias  = (const float*)d_in[4];
  const float* A_log    = (const float*)d_in[5];
  const float* Dvec     = (const float*)d_in[6];
  const float* mnorm_w  = (const float*)d_in[7];
  const float* out_proj = (const float*)d_in[8];
  const float* attn_w   = (const float*)d_in[9];
  const float* proj_w   = (const float*)d_in[10];
  const float* tmk      = (const float*)d_in[11];
  const float* tmr      = (const float*)d_in[12];
  const float* key_w    = (const float*)d_in[13];
  const float* recept_w = (const float*)d_in[14];
  const float* value_w  = (const float*)d_in[15];
  float* out = (float*)d_out;

  if (ws_size < 199229440ull) return;

  char* ws = (char*)d_ws;
  unsigned short* Wt   = (unsigned short*)(ws + 0);
  unsigned short* Abf  = (unsigned short*)(ws + 8912896ull);
  unsigned short* Abf2 = (unsigned short*)(ws + 42467328ull);
  float* bigF = (float*)(ws + 59244544ull);
  float* big1 = (float*)(ws + 95420416ull);
  float* big2 = (float*)(ws + 131072000ull);
  float* x1   = (float*)(ws + 164626432ull);
  float* xn3  = (float*)(ws + 181403648ull);
  float* dtb  = (float*)(ws + 198180864ull);
  float* labuf= (float*)(ws + 198705152ull);
  unsigned short* zbf  = Abf2;
  unsigned short* xkbf = Abf2;
  unsigned short* xrbf = Abf2 + 4194304;
  float* dhbuf = bigF;
  float* hseq  = (float*)Abf;
  unsigned short* qkvbf = (unsigned short*)big1;   // qkv as bf16 now

  dim3 b256(256);
  dim3 tb(32, 8);

  // ===== Phase A: mamba2 =====
  resrms_k<0, 0, 0><<<4096, b256, 0, stream>>>(x, nullptr, nullptr, Abf, nullptr);
  transp_k<<<dim3(64, 32), tb, 0, stream>>>(in_proj, Wt, 1024, 2048, 2048, 0, 4256);
  gemm4_k<1><<<512, b256, 0, stream>>>(Abf, Wt, zbf, 4096, 2048, 1024, 16);              // z (bf16)
  transp_k<<<dim3(72, 32), tb, 0, stream>>>(in_proj, Wt, 1024, 2208, 2304, 2048, 4256);
  gemm4_k<0><<<576, b256, 0, stream>>>(Abf, Wt, bigF, 4096, 2208, 1024, 18);             // xBC+dt (f32)
  convk<<<34816, b256, 0, stream>>>(bigF, conv_w, conv_b, dt_bias, big1, dtb);           // xbc_act + dt
  ssd1_k<<<2048, b256, 0, stream>>>(big1, dtb, A_log, big2, dhbuf, labuf);               // Y_intra, dh, la
  ssd2_k<<<2048, b256, 0, stream>>>(dhbuf, labuf, hseq);                                 // chunk states
  ssd3_k<<<2048, b256, 0, stream>>>(big1, hseq, labuf, Dvec, big2);                      // ydin final
  gnormk<<<4096, b256, 0, stream>>>(big2, zbf, mnorm_w, Abf);                            // g (bf16)
  transp_k<<<dim3(32, 64), tb, 0, stream>>>(out_proj, Wt, 2048, 1024, 1024, 0, 1024);
  gemm4_k<0><<<256, b256, 0, stream>>>(Abf, Wt, big1, 4096, 1024, 2048, 8);              // mo
  resrms_k<1, 1, 0><<<4096, b256, 0, stream>>>(x, big1, x1, Abf, nullptr);               // x1, xn2

  // ===== Phase B: mqa =====
  transp_k<<<dim3(36, 32), tb, 0, stream>>>(attn_w, Wt, 1024, 1152, 1152, 0, 1152);
  gemm4_k<1><<<288, b256, 0, stream>>>(Abf, Wt, qkvbf, 4096, 1152, 1024, 9);             // qkv (bf16)
  attnk<<<1024, b256, 0, stream>>>(qkvbf, Abf);                                          // atty (bf16)
  transp_k<<<dim3(32, 32), tb, 0, stream>>>(proj_w, Wt, 1024, 1024, 1024, 0, 1024);
  gemm4_k<0><<<256, b256, 0, stream>>>(Abf, Wt, big2, 4096, 1024, 1024, 8);              // po
  resrms_k<1, 1, 1><<<4096, b256, 0, stream>>>(x1, big2, x1, Abf, xn3);                  // x2 (in x1), xn3

  // ===== Phase C: cmix =====
  mixk<<<4096, b256, 0, stream>>>(xn3, tmk, tmr, xkbf, xrbf);
  transp_k<<<dim3(128, 32), tb, 0, stream>>>(key_w, Wt, 1024, 4096, 4096, 0, 4096);
  gemm4_k<2><<<1024, b256, 0, stream>>>(xkbf, Wt, Abf, 4096, 4096, 1024, 32);            // kact (bf16)
  transp_k<<<dim3(32, 128), tb, 0, stream>>>(value_w, Wt, 4096, 1024, 1024, 0, 1024);
  gemm4_k<0><<<256, b256, 0, stream>>>(Abf, Wt, big2, 4096, 1024, 4096, 8);              // vout
  transp_k<<<dim3(32, 32), tb, 0, stream>>>(recept_w, Wt, 1024, 1024, 1024, 0, 1024);
  gemm4_k<0><<<256, b256, 0, stream>>>(xrbf, Wt, big1, 4096, 1024, 1024, 8);             // rraw
  finalk<<<4096, b256, 0, stream>>>(x1, big1, big2, out);
}